// Round 1
// baseline (3313.497 us; speedup 1.0000x reference)
//
#include <hip/hip_runtime.h>
#include <math.h>

#define L_SEQ 2048
#define DIM   3072
#define NH    24
#define HD    128
#define RANK  16
#define N_QKV 9216
#define LORA_SC 1.0f

// ---------------------------------------------------------------------------
// T[l][r] = dot(X[l, :DIM], W[r, :DIM])   (rank-16 LoRA down-projection)
// ---------------------------------------------------------------------------
__global__ __launch_bounds__(256) void lora_down_kernel(
    const float* __restrict__ X, const float* __restrict__ W, float* __restrict__ T)
{
    int l = blockIdx.x;
    int r = threadIdx.x >> 4;      // 0..15
    int lane = threadIdx.x & 15;
    const float* xr = X + (size_t)l * DIM;
    const float* wr = W + (size_t)r * DIM;
    float s = 0.f;
    for (int k = lane; k < DIM; k += 16) s = fmaf(xr[k], wr[k], s);
    #pragma unroll
    for (int mm = 8; mm; mm >>= 1) s += __shfl_xor(s, mm, 64);
    if (lane == 0) T[l * RANK + r] = s;
}

// ---------------------------------------------------------------------------
// C = A @ Bw^T + bias + LORA_SC * (T @ Up^T)
// A: [M][K] row-major, Bw: [N][K] row-major, T: [M][16], Up: [N][16]
// SCATTER=1: write into qkv workspace laid out [3][NH][L][HD]
// SCATTER=0: plain [M][N]
// ---------------------------------------------------------------------------
template<int SCATTER>
__global__ __launch_bounds__(256) void gemm_lora_kernel(
    const float* __restrict__ A, const float* __restrict__ Bw,
    const float* __restrict__ bias, const float* __restrict__ T,
    const float* __restrict__ Up, float* __restrict__ C,
    int M, int N, int K)
{
    const int BM = 64, BN = 64, BK = 16, PITCH = BM + 4;  // 272B rows: 16B aligned
    __shared__ __align__(16) float a_s[BK][PITCH];
    __shared__ __align__(16) float b_s[BK][PITCH];

    int bm = blockIdx.y * BM, bn = blockIdx.x * BN;
    int tid = threadIdx.x;
    int tx = tid & 15, ty = tid >> 4;
    int sk = tid & 15, sm0 = tid >> 4;

    float acc[4][4] = {};

    const float* Arow = A + (size_t)bm * K + sk;
    const float* Brow = Bw + (size_t)bn * K + sk;

    for (int k0 = 0; k0 < K; k0 += BK) {
        #pragma unroll
        for (int i = 0; i < 4; i++) {
            int mrow = sm0 + 16 * i;
            a_s[sk][mrow] = Arow[(size_t)mrow * K + k0];
            b_s[sk][mrow] = Brow[(size_t)mrow * K + k0];
        }
        __syncthreads();
        #pragma unroll
        for (int kk = 0; kk < BK; kk++) {
            float4 av = *(const float4*)&a_s[kk][4 * ty];
            float4 bv = *(const float4*)&b_s[kk][4 * tx];
            float aa[4] = {av.x, av.y, av.z, av.w};
            float bb[4] = {bv.x, bv.y, bv.z, bv.w};
            #pragma unroll
            for (int ii = 0; ii < 4; ii++)
                #pragma unroll
                for (int jj = 0; jj < 4; jj++)
                    acc[ii][jj] = fmaf(aa[ii], bb[jj], acc[ii][jj]);
        }
        __syncthreads();
    }

    // epilogue: bias + rank-16 LoRA
    float tv[4][RANK], uv[4][RANK];
    #pragma unroll
    for (int ii = 0; ii < 4; ii++) {
        const float4* tp = (const float4*)(T + (size_t)(bm + 4 * ty + ii) * RANK);
        #pragma unroll
        for (int f = 0; f < 4; f++) {
            float4 v = tp[f];
            tv[ii][4*f+0] = v.x; tv[ii][4*f+1] = v.y; tv[ii][4*f+2] = v.z; tv[ii][4*f+3] = v.w;
        }
    }
    #pragma unroll
    for (int jj = 0; jj < 4; jj++) {
        const float4* up = (const float4*)(Up + (size_t)(bn + 4 * tx + jj) * RANK);
        #pragma unroll
        for (int f = 0; f < 4; f++) {
            float4 v = up[f];
            uv[jj][4*f+0] = v.x; uv[jj][4*f+1] = v.y; uv[jj][4*f+2] = v.z; uv[jj][4*f+3] = v.w;
        }
    }

    #pragma unroll
    for (int ii = 0; ii < 4; ii++) {
        int row = bm + 4 * ty + ii;
        #pragma unroll
        for (int jj = 0; jj < 4; jj++) {
            int col = bn + 4 * tx + jj;
            float lv = 0.f;
            #pragma unroll
            for (int r = 0; r < RANK; r++) lv = fmaf(tv[ii][r], uv[jj][r], lv);
            float val = acc[ii][jj] + bias[col] + LORA_SC * lv;
            if (SCATTER) {
                int mq  = col / DIM;          // 0=q 1=k 2=v
                int rem = col - mq * DIM;
                int hh  = rem >> 7;           // /128
                int dd  = rem & 127;
                C[(((size_t)(mq * NH + hh)) * L_SEQ + row) * HD + dd] = val;
            } else {
                C[(size_t)row * N + col] = val;
            }
        }
    }
}

// ---------------------------------------------------------------------------
// In-place per-head RMSNorm + RoPE on q (blockIdx.y==0) / k (==1).
// qkv layout [3][NH][L][HD]; one wave per (h,l) row.
// ---------------------------------------------------------------------------
__global__ __launch_bounds__(256) void rmsrope_kernel(
    float* __restrict__ qkv, const float* __restrict__ pe,
    const float* __restrict__ q_scale, const float* __restrict__ k_scale)
{
    int wave = threadIdx.x >> 6;
    int lane = threadIdx.x & 63;
    int row = blockIdx.x * 4 + wave;               // h*L + l
    int which = blockIdx.y;                        // 0=q, 1=k
    const float* scale = which ? k_scale : q_scale;
    float* base = qkv + ((size_t)which * NH * L_SEQ + row) * HD;
    int l = row & (L_SEQ - 1);

    float2 t = *(const float2*)(base + 2 * lane);
    float ss = t.x * t.x + t.y * t.y;
    #pragma unroll
    for (int mm = 32; mm; mm >>= 1) ss += __shfl_xor(ss, mm, 64);
    float rn = rsqrtf(ss * (1.0f / HD) + 1e-6f);
    float t0 = t.x * rn * scale[2 * lane];
    float t1 = t.y * rn * scale[2 * lane + 1];
    float4 p = *(const float4*)(pe + ((size_t)l * 64 + lane) * 4);
    float2 o;
    o.x = p.x * t0 + p.y * t1;
    o.y = p.z * t0 + p.w * t1;
    *(float2*)(base + 2 * lane) = o;
}

// ---------------------------------------------------------------------------
// fp32 flash attention. Block = (q-tile of 64 rows) x (one head).
// Q staged transposed q_s[d][i]; K staged transposed kv_s[d][j]; after S,
// V overwrites kv_s in natural [j][d] layout. P round-trips through p_s[i][j].
// Output written as O[l][h*HD + d]  (the [B,L,H*HD] layout proj wants).
// ---------------------------------------------------------------------------
__global__ __launch_bounds__(256) void attn_kernel(
    const float* __restrict__ qkv, float* __restrict__ Og)
{
    __shared__ __align__(16) float q_s[HD * 64];   // 32 KB  [d][i]
    __shared__ __align__(16) float kv_s[64 * HD];  // 32 KB  K:[d][j] then V:[j][d]
    __shared__ __align__(16) float p_s[64 * 64];   // 16 KB  [i][j]

    int h  = blockIdx.y;
    int q0 = blockIdx.x * 64;
    const float* qb = qkv + (size_t)h * L_SEQ * HD;
    const float* kb = qkv + ((size_t)(NH + h)) * L_SEQ * HD;
    const float* vb = qkv + ((size_t)(2 * NH + h)) * L_SEQ * HD;
    int tid = threadIdx.x;
    int tx = tid & 15, ty = tid >> 4;

    // stage Q transposed (once per block)
    {
        int i = tid >> 2;
        int dbase = (tid & 3) * 32;
        const float* src = qb + (size_t)(q0 + i) * HD + dbase;
        #pragma unroll
        for (int f = 0; f < 8; f++) {
            float4 v = *(const float4*)(src + 4 * f);
            int d = dbase + 4 * f;
            q_s[(d + 0) * 64 + i] = v.x;
            q_s[(d + 1) * 64 + i] = v.y;
            q_s[(d + 2) * 64 + i] = v.z;
            q_s[(d + 3) * 64 + i] = v.w;
        }
    }

    float o_acc[4][8] = {};
    float m_run[4], l_run[4];
    #pragma unroll
    for (int ii = 0; ii < 4; ii++) { m_run[ii] = -INFINITY; l_run[ii] = 0.f; }
    const float sm_scale = 0.08838834764831845f;   // 1/sqrt(128)

    for (int kv0 = 0; kv0 < L_SEQ; kv0 += 64) {
        __syncthreads();   // prev PV done with kv_s/p_s; also covers q_s staging on iter 0
        // stage K transposed
        {
            int j = tid >> 2;
            int dbase = (tid & 3) * 32;
            const float* src = kb + (size_t)(kv0 + j) * HD + dbase;
            #pragma unroll
            for (int f = 0; f < 8; f++) {
                float4 v = *(const float4*)(src + 4 * f);
                int d = dbase + 4 * f;
                kv_s[(d + 0) * 64 + j] = v.x;
                kv_s[(d + 1) * 64 + j] = v.y;
                kv_s[(d + 2) * 64 + j] = v.z;
                kv_s[(d + 3) * 64 + j] = v.w;
            }
        }
        __syncthreads();

        // S = Q K^T (per thread 4x4)
        float s_t[4][4] = {};
        for (int d = 0; d < HD; d++) {
            float4 qv = *(const float4*)&q_s[d * 64 + 4 * ty];
            float4 kv = *(const float4*)&kv_s[d * 64 + 4 * tx];
            float qa[4] = {qv.x, qv.y, qv.z, qv.w};
            float ka[4] = {kv.x, kv.y, kv.z, kv.w};
            #pragma unroll
            for (int ii = 0; ii < 4; ii++)
                #pragma unroll
                for (int jj = 0; jj < 4; jj++)
                    s_t[ii][jj] = fmaf(qa[ii], ka[jj], s_t[ii][jj]);
        }

        // online softmax
        float p_t[4][4];
        #pragma unroll
        for (int ii = 0; ii < 4; ii++) {
            float rmax = -INFINITY;
            #pragma unroll
            for (int jj = 0; jj < 4; jj++) {
                s_t[ii][jj] *= sm_scale;
                rmax = fmaxf(rmax, s_t[ii][jj]);
            }
            #pragma unroll
            for (int mm = 8; mm; mm >>= 1) rmax = fmaxf(rmax, __shfl_xor(rmax, mm, 64));
            float m_new = fmaxf(m_run[ii], rmax);
            float alpha = expf(m_run[ii] - m_new);
            float psum = 0.f;
            #pragma unroll
            for (int jj = 0; jj < 4; jj++) {
                p_t[ii][jj] = expf(s_t[ii][jj] - m_new);
                psum += p_t[ii][jj];
            }
            #pragma unroll
            for (int mm = 8; mm; mm >>= 1) psum += __shfl_xor(psum, mm, 64);
            l_run[ii] = l_run[ii] * alpha + psum;
            m_run[ii] = m_new;
            #pragma unroll
            for (int c = 0; c < 8; c++) o_acc[ii][c] *= alpha;
        }

        // write P tile
        #pragma unroll
        for (int ii = 0; ii < 4; ii++) {
            float4 pv = {p_t[ii][0], p_t[ii][1], p_t[ii][2], p_t[ii][3]};
            *(float4*)&p_s[(4 * ty + ii) * 64 + 4 * tx] = pv;
        }
        __syncthreads();

        // stage V over kv_s (natural [j][d])
        {
            const float4* src = (const float4*)(vb + (size_t)kv0 * HD);
            float4* dst = (float4*)kv_s;
            #pragma unroll
            for (int f = 0; f < 8; f++) dst[tid + 256 * f] = src[tid + 256 * f];
        }
        __syncthreads();

        // O += P V  (thread covers d = 4tx..4tx+3 and 64+4tx..+3)
        for (int j0 = 0; j0 < 64; j0 += 4) {
            float pr[4][4];
            #pragma unroll
            for (int ii = 0; ii < 4; ii++) {
                float4 t = *(const float4*)&p_s[(4 * ty + ii) * 64 + j0];
                pr[ii][0] = t.x; pr[ii][1] = t.y; pr[ii][2] = t.z; pr[ii][3] = t.w;
            }
            #pragma unroll
            for (int jj = 0; jj < 4; jj++) {
                int j = j0 + jj;
                float4 va = *(const float4*)&kv_s[j * HD + 4 * tx];
                float4 vb4 = *(const float4*)&kv_s[j * HD + 64 + 4 * tx];
                float va_[4] = {va.x, va.y, va.z, va.w};
                float vb_[4] = {vb4.x, vb4.y, vb4.z, vb4.w};
                #pragma unroll
                for (int ii = 0; ii < 4; ii++) {
                    #pragma unroll
                    for (int c = 0; c < 4; c++) {
                        o_acc[ii][c]     = fmaf(pr[ii][jj], va_[c], o_acc[ii][c]);
                        o_acc[ii][c + 4] = fmaf(pr[ii][jj], vb_[c], o_acc[ii][c + 4]);
                    }
                }
            }
        }
    }

    // normalize + write O in [L][H*HD] layout
    #pragma unroll
    for (int ii = 0; ii < 4; ii++) {
        float invl = 1.f / l_run[ii];
        int row = q0 + 4 * ty + ii;
        float4 o1 = {o_acc[ii][0] * invl, o_acc[ii][1] * invl,
                     o_acc[ii][2] * invl, o_acc[ii][3] * invl};
        float4 o2 = {o_acc[ii][4] * invl, o_acc[ii][5] * invl,
                     o_acc[ii][6] * invl, o_acc[ii][7] * invl};
        *(float4*)(Og + (size_t)row * DIM + h * HD + 4 * tx) = o1;
        *(float4*)(Og + (size_t)row * DIM + h * HD + 64 + 4 * tx) = o2;
    }
}

// ---------------------------------------------------------------------------
extern "C" void kernel_launch(void* const* d_in, const int* in_sizes, int n_in,
                              void* d_out, int out_size, void* d_ws, size_t ws_size,
                              hipStream_t stream)
{
    const float* x         = (const float*)d_in[0];
    const float* pe        = (const float*)d_in[1];
    const float* qkv_w     = (const float*)d_in[2];
    const float* qkv_b     = (const float*)d_in[3];
    const float* proj_w    = (const float*)d_in[4];
    const float* proj_b    = (const float*)d_in[5];
    const float* qkv_down  = (const float*)d_in[6];
    const float* qkv_up    = (const float*)d_in[7];
    const float* proj_down = (const float*)d_in[8];
    const float* proj_up   = (const float*)d_in[9];
    const float* q_scale   = (const float*)d_in[10];
    const float* k_scale   = (const float*)d_in[11];
    float* out = (float*)d_out;

    float* qkv_ws = (float*)d_ws;                          // [3][NH][L][HD]  75.5 MB
    float* o_ws   = qkv_ws + (size_t)3 * NH * L_SEQ * HD;  // [L][DIM]        25.2 MB
    float* t1     = o_ws + (size_t)L_SEQ * DIM;            // [L][16]
    float* t2     = t1 + (size_t)L_SEQ * RANK;             // [L][16]

    lora_down_kernel<<<L_SEQ, 256, 0, stream>>>(x, qkv_down, t1);
    gemm_lora_kernel<1><<<dim3(N_QKV / 64, L_SEQ / 64), 256, 0, stream>>>(
        x, qkv_w, qkv_b, t1, qkv_up, qkv_ws, L_SEQ, N_QKV, DIM);
    rmsrope_kernel<<<dim3(NH * L_SEQ / 4, 2), 256, 0, stream>>>(qkv_ws, pe, q_scale, k_scale);
    attn_kernel<<<dim3(L_SEQ / 64, NH), 256, 0, stream>>>(qkv_ws, o_ws);
    lora_down_kernel<<<L_SEQ, 256, 0, stream>>>(o_ws, proj_down, t2);
    gemm_lora_kernel<0><<<dim3(DIM / 64, L_SEQ / 64), 256, 0, stream>>>(
        o_ws, proj_w, proj_b, t2, proj_up, out, L_SEQ, DIM, DIM);
}

// Round 2
// 1860.441 us; speedup vs baseline: 1.7810x; 1.7810x over previous
//
#include <hip/hip_runtime.h>
#include <math.h>

#define L_SEQ 2048
#define DIM   3072
#define NH    24
#define HD    128
#define RANK  16
#define N_QKV 9216

typedef __attribute__((ext_vector_type(8))) short bf16x8;
typedef __attribute__((ext_vector_type(4))) float f32x4;
typedef unsigned short u16;
typedef unsigned int u32;

__device__ __forceinline__ u16 f2bf(float f) {
    union { float f; u32 u; } v; v.f = f;
    return (u16)((v.u + 0x7fffu + ((v.u >> 16) & 1u)) >> 16);
}
__device__ __forceinline__ float bf2f(u16 h) {
    union { u32 u; float f; } v; v.u = ((u32)h) << 16; return v.f;
}

#define GLOBAL_TO_LDS16(gp, lp) \
  __builtin_amdgcn_global_load_lds((const __attribute__((address_space(1))) u32*)(gp), \
                                   (__attribute__((address_space(3))) u32*)(lp), 16, 0, 0)

// ---------------------------------------------------------------------------
// fp32 -> bf16 convert (RNE), vectorized grid-stride
// ---------------------------------------------------------------------------
__global__ __launch_bounds__(256) void convert_bf16_kernel(
    const float* __restrict__ in, u16* __restrict__ out, int n)
{
    int stride = gridDim.x * 256 * 4;
    for (int i = (blockIdx.x * 256 + threadIdx.x) * 4; i < n; i += stride) {
        float4 v = *(const float4*)(in + i);
        ushort4 o;
        o.x = f2bf(v.x); o.y = f2bf(v.y); o.z = f2bf(v.z); o.w = f2bf(v.w);
        *(ushort4*)(out + i) = o;
    }
}

// ---------------------------------------------------------------------------
// T[l][r] = dot(X[l,:], W[r,:])  rank-16 LoRA down; fp32 input variant
// ---------------------------------------------------------------------------
__global__ __launch_bounds__(256) void lora_down_kernel(
    const float* __restrict__ X, const float* __restrict__ W, float* __restrict__ T)
{
    int l = blockIdx.x;
    int r = threadIdx.x >> 4;
    int lane = threadIdx.x & 15;
    const float* xr = X + (size_t)l * DIM;
    const float* wr = W + (size_t)r * DIM;
    float s = 0.f;
    for (int k = lane; k < DIM; k += 16) s = fmaf(xr[k], wr[k], s);
    #pragma unroll
    for (int mm = 8; mm; mm >>= 1) s += __shfl_xor(s, mm);
    if (lane == 0) T[l * RANK + r] = s;
}

// bf16 input variant (for o)
__global__ __launch_bounds__(256) void lora_down_bf_kernel(
    const u16* __restrict__ X, const float* __restrict__ W, float* __restrict__ T)
{
    int l = blockIdx.x;
    int r = threadIdx.x >> 4;
    int lane = threadIdx.x & 15;
    const u16* xr = X + (size_t)l * DIM;
    const float* wr = W + (size_t)r * DIM;
    float s = 0.f;
    for (int k = lane; k < DIM; k += 16) s = fmaf(bf2f(xr[k]), wr[k], s);
    #pragma unroll
    for (int mm = 8; mm; mm >>= 1) s += __shfl_xor(s, mm);
    if (lane == 0) T[l * RANK + r] = s;
}

// ---------------------------------------------------------------------------
// bf16 MFMA GEMM: C = A @ W^T + bias + T @ Up^T   (A:[M][K], W:[N][K] bf16)
// 128x128 tile, BK=32, mfma_f32_16x16x32_bf16, global_load_lds staging with
// XOR k-chunk swizzle (chunk' = chunk ^ ((row>>1)&3)) for bank-conflict-free
// ds_read_b128 fragment loads.
// SCATTER=1: write qkv workspace [3][NH][L][HD] fp32; SCATTER=0: [M][N] fp32.
// ---------------------------------------------------------------------------
template<int SCATTER>
__global__ __launch_bounds__(256) void gemm_mfma_kernel(
    const u16* __restrict__ A, const u16* __restrict__ W,
    const float* __restrict__ bias, const float* __restrict__ T,
    const float* __restrict__ Up, float* __restrict__ C,
    int M, int N, int K)
{
    __shared__ __align__(16) u16 a_s[128 * 32];   // [row][32k], 64B rows, swizzled
    __shared__ __align__(16) u16 b_s[128 * 32];

    int tid = threadIdx.x;
    int wave = tid >> 6, lane = tid & 63;
    int quad = lane >> 4, l15 = lane & 15;
    int wm = wave >> 1, wn = wave & 1;
    int bm = blockIdx.y * 128, bn = blockIdx.x * 128;

    // staging source pointers (lane-dependent), LDS bases (wave-uniform)
    const u16* ga[2]; const u16* gb[2];
    #pragma unroll
    for (int e = 0; e < 2; e++) {
        int r = wave * 32 + e * 16 + (lane >> 2);
        int g = (lane & 3) ^ ((r >> 1) & 3);
        ga[e] = A + (size_t)(bm + r) * K + g * 8;
        gb[e] = W + (size_t)(bn + r) * K + g * 8;
    }
    u16* lA[2] = { &a_s[(wave * 32 + 0) * 32], &a_s[(wave * 32 + 16) * 32] };
    u16* lB[2] = { &b_s[(wave * 32 + 0) * 32], &b_s[(wave * 32 + 16) * 32] };

    f32x4 acc[4][4];
    #pragma unroll
    for (int i = 0; i < 4; i++)
        #pragma unroll
        for (int j = 0; j < 4; j++) acc[i][j] = (f32x4){0.f, 0.f, 0.f, 0.f};

    // precompute fragment LDS byte offsets
    int aoff[4], boff[4];
    #pragma unroll
    for (int i = 0; i < 4; i++) {
        int r = wm * 64 + i * 16 + l15;
        aoff[i] = r * 32 + (quad ^ ((r >> 1) & 3)) * 8;
        int rb = wn * 64 + i * 16 + l15;
        boff[i] = rb * 32 + (quad ^ ((rb >> 1) & 3)) * 8;
    }

    for (int k0 = 0; k0 < K; k0 += 32) {
        #pragma unroll
        for (int e = 0; e < 2; e++) {
            GLOBAL_TO_LDS16(ga[e] + k0, lA[e]);
            GLOBAL_TO_LDS16(gb[e] + k0, lB[e]);
        }
        __syncthreads();
        bf16x8 af[4], bf[4];
        #pragma unroll
        for (int i = 0; i < 4; i++) af[i] = *(const bf16x8*)&a_s[aoff[i]];
        #pragma unroll
        for (int j = 0; j < 4; j++) bf[j] = *(const bf16x8*)&b_s[boff[j]];
        #pragma unroll
        for (int i = 0; i < 4; i++)
            #pragma unroll
            for (int j = 0; j < 4; j++)
                acc[i][j] = __builtin_amdgcn_mfma_f32_16x16x32_bf16(af[i], bf[j], acc[i][j], 0, 0, 0);
        __syncthreads();
    }

    // epilogue: bias + rank-16 LoRA, fp32
    #pragma unroll
    for (int j = 0; j < 4; j++) {
        int col = bn + wn * 64 + j * 16 + l15;
        const float4* up = (const float4*)(Up + (size_t)col * RANK);
        float4 u0 = up[0], u1 = up[1], u2 = up[2], u3 = up[3];
        float bj = bias[col];
        int mq = 0, rem = col;
        if (SCATTER) {
            mq = (col >= 2 * DIM) ? 2 : (col >= DIM ? 1 : 0);
            rem = col - mq * DIM;
        }
        int hh = rem >> 7, dd = rem & 127;
        #pragma unroll
        for (int i = 0; i < 4; i++) {
            #pragma unroll
            for (int r = 0; r < 4; r++) {
                int row = bm + wm * 64 + i * 16 + quad * 4 + r;
                const float4* tp = (const float4*)(T + (size_t)row * RANK);
                float4 t0 = tp[0], t1 = tp[1], t2 = tp[2], t3 = tp[3];
                float lv = t0.x*u0.x + t0.y*u0.y + t0.z*u0.z + t0.w*u0.w
                         + t1.x*u1.x + t1.y*u1.y + t1.z*u1.z + t1.w*u1.w
                         + t2.x*u2.x + t2.y*u2.y + t2.z*u2.z + t2.w*u2.w
                         + t3.x*u3.x + t3.y*u3.y + t3.z*u3.z + t3.w*u3.w;
                float val = acc[i][j][r] + bj + lv;
                if (SCATTER)
                    C[(((size_t)(mq * NH + hh)) * L_SEQ + row) * HD + dd] = val;
                else
                    C[(size_t)row * N + col] = val;
            }
        }
    }
}

// ---------------------------------------------------------------------------
// RMSNorm + RoPE (q,k) / convert (v): fp32 qkv [3][NH][L][HD] -> bf16 same layout
// ---------------------------------------------------------------------------
__global__ __launch_bounds__(256) void rmsrope_kernel(
    const float* __restrict__ qkv, u16* __restrict__ qkv_bf,
    const float* __restrict__ pe,
    const float* __restrict__ q_scale, const float* __restrict__ k_scale)
{
    int wave = threadIdx.x >> 6;
    int lane = threadIdx.x & 63;
    int row = blockIdx.x * 4 + wave;               // h*L + l
    int which = blockIdx.y;                        // 0=q 1=k 2=v
    const float* base = qkv + ((size_t)which * NH * L_SEQ + row) * HD;
    u16* obase = qkv_bf + ((size_t)which * NH * L_SEQ + row) * HD;
    float2 t = *(const float2*)(base + 2 * lane);
    if (which == 2) {
        obase[2 * lane]     = f2bf(t.x);
        obase[2 * lane + 1] = f2bf(t.y);
        return;
    }
    const float* scale = which ? k_scale : q_scale;
    int l = row & (L_SEQ - 1);
    float ss = t.x * t.x + t.y * t.y;
    #pragma unroll
    for (int mm = 32; mm; mm >>= 1) ss += __shfl_xor(ss, mm);
    float rn = rsqrtf(ss * (1.0f / HD) + 1e-6f);
    float t0 = t.x * rn * scale[2 * lane];
    float t1 = t.y * rn * scale[2 * lane + 1];
    float4 p = *(const float4*)(pe + ((size_t)l * 64 + lane) * 4);
    obase[2 * lane]     = f2bf(p.x * t0 + p.y * t1);
    obase[2 * lane + 1] = f2bf(p.z * t0 + p.w * t1);
}

// ---------------------------------------------------------------------------
// bf16 MFMA flash attention. Block = 256 thr (4 waves) x one head x 64 q-rows.
// Wave handles 16 q-rows. KV tiles of 64. K staged via global_load_lds with
// XOR-16 chunk swizzle; V staged transposed (pitch 72); P via per-wave LDS
// (pitch 72) for C-layout -> A-layout. Output bf16 [L][DIM].
// ---------------------------------------------------------------------------
__global__ __launch_bounds__(256) void attn_mfma_kernel(
    const u16* __restrict__ qkv_bf, u16* __restrict__ Og)
{
    __shared__ __align__(16) u16 k_s[64 * 128];    // 16 KB, row=kv, 16 chunks swizzled
    __shared__ __align__(16) u16 v_s[128 * 72];    // 18 KB, [d][kv] pitch 72
    __shared__ __align__(16) u16 p_s[4][16 * 72];  // 9 KB, per-wave [m][kv] pitch 72

    int h = blockIdx.y;
    int q0 = blockIdx.x * 64;
    int tid = threadIdx.x;
    int wave = tid >> 6, lane = tid & 63;
    int quad = lane >> 4, l15 = lane & 15;
    const u16* qb = qkv_bf + (size_t)h * L_SEQ * HD;
    const u16* kb = qkv_bf + (size_t)(NH + h) * L_SEQ * HD;
    const u16* vb = qkv_bf + (size_t)(2 * NH + h) * L_SEQ * HD;

    // Q fragments in registers: A[m=l15][k], m-tile = wave
    bf16x8 aq[4];
    {
        const u16* qr = qb + (size_t)(q0 + wave * 16 + l15) * HD + quad * 8;
        #pragma unroll
        for (int ks = 0; ks < 4; ks++) aq[ks] = *(const bf16x8*)(qr + ks * 32);
    }

    f32x4 o_acc[8];
    #pragma unroll
    for (int n = 0; n < 8; n++) o_acc[n] = (f32x4){0.f, 0.f, 0.f, 0.f};
    float m_run[4] = {-1e30f, -1e30f, -1e30f, -1e30f};
    float l_run[4] = {0.f, 0.f, 0.f, 0.f};
    const float sc = 0.08838834764831845f * 1.4426950408889634f;  // 1/sqrt(128) * log2(e)

    // K staging source (lane-dependent): 4 issues x 4 rows per wave
    const u16* gk[4];
    #pragma unroll
    for (int e = 0; e < 4; e++) {
        int r = wave * 16 + e * 4 + (lane >> 4);
        int g = l15 ^ (r & 15);
        gk[e] = kb + (size_t)r * HD + g * 8;
    }

    for (int kv0 = 0; kv0 < L_SEQ; kv0 += 64) {
        __syncthreads();
        // stage K tile (swizzled copy)
        #pragma unroll
        for (int e = 0; e < 4; e++)
            GLOBAL_TO_LDS16(gk[e] + (size_t)kv0 * HD, &k_s[(wave * 16 + e * 4) * 128]);
        // stage V transposed
        {
            int r = tid >> 2;
            int c0 = (tid & 3) * 8;
            const u16* vr = vb + (size_t)(kv0 + r) * HD;
            #pragma unroll
            for (int it = 0; it < 4; it++) {
                int d0 = c0 + it * 32;
                uint4 v = *(const uint4*)(vr + d0);
                v_s[(d0 + 0) * 72 + r] = (u16)(v.x);
                v_s[(d0 + 1) * 72 + r] = (u16)(v.x >> 16);
                v_s[(d0 + 2) * 72 + r] = (u16)(v.y);
                v_s[(d0 + 3) * 72 + r] = (u16)(v.y >> 16);
                v_s[(d0 + 4) * 72 + r] = (u16)(v.z);
                v_s[(d0 + 5) * 72 + r] = (u16)(v.z >> 16);
                v_s[(d0 + 6) * 72 + r] = (u16)(v.w);
                v_s[(d0 + 7) * 72 + r] = (u16)(v.w >> 16);
            }
        }
        __syncthreads();

        // S = Q K^T : 4 n-tiles x 4 k-steps
        f32x4 sacc[4];
        #pragma unroll
        for (int j = 0; j < 4; j++) sacc[j] = (f32x4){0.f, 0.f, 0.f, 0.f};
        #pragma unroll
        for (int ks = 0; ks < 4; ks++) {
            #pragma unroll
            for (int j = 0; j < 4; j++) {
                int n = j * 16 + l15;                    // kv index in tile
                int slot = (ks * 4 + quad) ^ (n & 15);
                bf16x8 bk = *(const bf16x8*)&k_s[n * 128 + slot * 8];
                sacc[j] = __builtin_amdgcn_mfma_f32_16x16x32_bf16(aq[ks], bk, sacc[j], 0, 0, 0);
            }
        }

        // online softmax (rows = quad*4+r)
        float alpha[4];
        #pragma unroll
        for (int r = 0; r < 4; r++) {
            float rmax = fmaxf(fmaxf(sacc[0][r], sacc[1][r]), fmaxf(sacc[2][r], sacc[3][r]));
            #pragma unroll
            for (int mm = 8; mm; mm >>= 1) rmax = fmaxf(rmax, __shfl_xor(rmax, mm));
            float m_new = fmaxf(m_run[r], rmax);
            alpha[r] = exp2f((m_run[r] - m_new) * sc);
            m_run[r] = m_new;
            float ps = 0.f;
            #pragma unroll
            for (int j = 0; j < 4; j++) {
                float p = exp2f((sacc[j][r] - m_new) * sc);
                sacc[j][r] = p;
                ps += p;
            }
            #pragma unroll
            for (int mm = 8; mm; mm >>= 1) ps += __shfl_xor(ps, mm);
            l_run[r] = l_run[r] * alpha[r] + ps;
        }

        // P: C-layout -> A-layout via per-wave LDS
        #pragma unroll
        for (int j = 0; j < 4; j++)
            #pragma unroll
            for (int r = 0; r < 4; r++)
                p_s[wave][(quad * 4 + r) * 72 + j * 16 + l15] = f2bf(sacc[j][r]);
        bf16x8 ap[2];
        #pragma unroll
        for (int ks = 0; ks < 2; ks++)
            ap[ks] = *(const bf16x8*)&p_s[wave][l15 * 72 + ks * 32 + quad * 8];

        // rescale O, then O += P V
        #pragma unroll
        for (int n = 0; n < 8; n++)
            #pragma unroll
            for (int r = 0; r < 4; r++) o_acc[n][r] *= alpha[r];
        #pragma unroll
        for (int ks = 0; ks < 2; ks++) {
            #pragma unroll
            for (int n = 0; n < 8; n++) {
                bf16x8 bv = *(const bf16x8*)&v_s[(n * 16 + l15) * 72 + ks * 32 + quad * 8];
                o_acc[n] = __builtin_amdgcn_mfma_f32_16x16x32_bf16(ap[ks], bv, o_acc[n], 0, 0, 0);
            }
        }
    }

    // normalize + write O bf16 in [L][H*HD]
    #pragma unroll
    for (int r = 0; r < 4; r++) {
        float inv = 1.f / l_run[r];
        int row = q0 + wave * 16 + quad * 4 + r;
        u16* orow = Og + (size_t)row * DIM + h * HD;
        #pragma unroll
        for (int n = 0; n < 8; n++)
            orow[n * 16 + l15] = f2bf(o_acc[n][r] * inv);
    }
}

// ---------------------------------------------------------------------------
extern "C" void kernel_launch(void* const* d_in, const int* in_sizes, int n_in,
                              void* d_out, int out_size, void* d_ws, size_t ws_size,
                              hipStream_t stream)
{
    const float* x         = (const float*)d_in[0];
    const float* pe        = (const float*)d_in[1];
    const float* qkv_w     = (const float*)d_in[2];
    const float* qkv_b     = (const float*)d_in[3];
    const float* proj_w    = (const float*)d_in[4];
    const float* proj_b    = (const float*)d_in[5];
    const float* qkv_down  = (const float*)d_in[6];
    const float* qkv_up    = (const float*)d_in[7];
    const float* proj_down = (const float*)d_in[8];
    const float* proj_up   = (const float*)d_in[9];
    const float* q_scale   = (const float*)d_in[10];
    const float* k_scale   = (const float*)d_in[11];
    float* out = (float*)d_out;

    const size_t QKV_ELEMS = (size_t)3 * NH * L_SEQ * HD;   // 18.87M
    char* w = (char*)d_ws;
    float* qkv_f  = (float*)w;                         w += QKV_ELEMS * 4;          // 75.5 MB
    u16*   qkv_bf = (u16*)w;                           w += QKV_ELEMS * 2;          // 37.7 MB
    u16*   x_bf   = (u16*)w;                           w += (size_t)L_SEQ * DIM * 2;
    u16*   wq_bf  = (u16*)w;                           w += (size_t)N_QKV * DIM * 2; // 56.6 MB
    u16*   wp_bf  = (u16*)w;                           w += (size_t)DIM * DIM * 2;   // 18.9 MB
    u16*   o_bf   = (u16*)w;                           w += (size_t)L_SEQ * DIM * 2;
    float* t1     = (float*)w;                         w += (size_t)L_SEQ * RANK * 4;
    float* t2     = (float*)w;

    convert_bf16_kernel<<<2048, 256, 0, stream>>>(x, x_bf, L_SEQ * DIM);
    convert_bf16_kernel<<<2048, 256, 0, stream>>>(qkv_w, wq_bf, N_QKV * DIM);
    convert_bf16_kernel<<<2048, 256, 0, stream>>>(proj_w, wp_bf, DIM * DIM);

    lora_down_kernel<<<L_SEQ, 256, 0, stream>>>(x, qkv_down, t1);
    gemm_mfma_kernel<1><<<dim3(N_QKV / 128, L_SEQ / 128), 256, 0, stream>>>(
        x_bf, wq_bf, qkv_b, t1, qkv_up, qkv_f, L_SEQ, N_QKV, DIM);
    rmsrope_kernel<<<dim3(NH * L_SEQ / 4, 3), 256, 0, stream>>>(
        qkv_f, qkv_bf, pe, q_scale, k_scale);
    attn_mfma_kernel<<<dim3(L_SEQ / 64, NH), 256, 0, stream>>>(qkv_bf, o_bf);
    lora_down_bf_kernel<<<L_SEQ, 256, 0, stream>>>(o_bf, proj_down, t2);
    gemm_mfma_kernel<0><<<dim3(DIM / 128, L_SEQ / 128), 256, 0, stream>>>(
        o_bf, wp_bf, proj_b, t2, proj_up, out, L_SEQ, DIM, DIM);
}

// Round 3
// 911.630 us; speedup vs baseline: 3.6347x; 2.0408x over previous
//
#include <hip/hip_runtime.h>
#include <math.h>

#define L_SEQ 2048
#define DIM   3072
#define NH    24
#define HD    128
#define RANK  16
#define N_QKV 9216
#define KE    3104   // DIM + 16 (T_hi|Up) + 16 (T_lo|Up), multiple of 32

typedef __attribute__((ext_vector_type(8))) short bf16x8;
typedef __attribute__((ext_vector_type(4))) float f32x4;
typedef unsigned short u16;
typedef unsigned int u32;

__device__ __forceinline__ u16 f2bf(float f) {
    union { float f; u32 u; } v; v.f = f;
    return (u16)((v.u + 0x7fffu + ((v.u >> 16) & 1u)) >> 16);
}
__device__ __forceinline__ float bf2f(u16 h) {
    union { u32 u; float f; } v; v.u = ((u32)h) << 16; return v.f;
}

#define GLOBAL_TO_LDS16(gp, lp) \
  __builtin_amdgcn_global_load_lds((const __attribute__((address_space(1))) u32*)(gp), \
                                   (__attribute__((address_space(3))) u32*)(lp), 16, 0, 0)

// ---------------------------------------------------------------------------
// T[l][r] = dot(X[l,:DIM], W[r,:DIM])  rank-16 LoRA down (fp32 X)
// ---------------------------------------------------------------------------
__global__ __launch_bounds__(256) void lora_down_kernel(
    const float* __restrict__ X, const float* __restrict__ W, float* __restrict__ T)
{
    int l = blockIdx.x;
    int r = threadIdx.x >> 4;
    int lane = threadIdx.x & 15;
    const float* xr = X + (size_t)l * DIM;
    const float* wr = W + (size_t)r * DIM;
    float s = 0.f;
    for (int k = lane; k < DIM; k += 16) s = fmaf(xr[k], wr[k], s);
    #pragma unroll
    for (int mm = 8; mm; mm >>= 1) s += __shfl_xor(s, mm);
    if (lane == 0) T[l * RANK + r] = s;
}

// bf16-X variant with row pitch (for o_ext)
__global__ __launch_bounds__(256) void lora_down_bf_kernel(
    const u16* __restrict__ X, const float* __restrict__ W, float* __restrict__ T, int pitch)
{
    int l = blockIdx.x;
    int r = threadIdx.x >> 4;
    int lane = threadIdx.x & 15;
    const u16* xr = X + (size_t)l * pitch;
    const float* wr = W + (size_t)r * DIM;
    float s = 0.f;
    for (int k = lane; k < DIM; k += 16) s = fmaf(bf2f(xr[k]), wr[k], s);
    #pragma unroll
    for (int mm = 8; mm; mm >>= 1) s += __shfl_xor(s, mm);
    if (lane == 0) T[l * RANK + r] = s;
}

// ---------------------------------------------------------------------------
// pack weights: out[row][0:DIM)=bf16(W row), [DIM,DIM+16)=Up, [DIM+16,DIM+32)=Up
// ---------------------------------------------------------------------------
__global__ __launch_bounds__(256) void pack_w_kernel(
    const float* __restrict__ W, const float* __restrict__ Up, u16* __restrict__ out)
{
    int row = blockIdx.x;
    const float* wr = W + (size_t)row * DIM;
    u16* orow = out + (size_t)row * KE;
    #pragma unroll
    for (int it = 0; it < 3; it++) {
        int c4 = threadIdx.x + it * 256;
        float4 v = ((const float4*)wr)[c4];
        ushort4 o = {f2bf(v.x), f2bf(v.y), f2bf(v.z), f2bf(v.w)};
        *(ushort4*)(orow + c4 * 4) = o;
    }
    if (threadIdx.x < RANK) {
        u16 b = f2bf(Up[row * RANK + threadIdx.x]);
        orow[DIM + threadIdx.x] = b;
        orow[DIM + RANK + threadIdx.x] = b;
    }
}

// pack activations: out[row][0:DIM)=bf16(X row), then T split hi/lo
__global__ __launch_bounds__(256) void pack_x_kernel(
    const float* __restrict__ X, const float* __restrict__ T, u16* __restrict__ out)
{
    int row = blockIdx.x;
    const float* xr = X + (size_t)row * DIM;
    u16* orow = out + (size_t)row * KE;
    #pragma unroll
    for (int it = 0; it < 3; it++) {
        int c4 = threadIdx.x + it * 256;
        float4 v = ((const float4*)xr)[c4];
        ushort4 o = {f2bf(v.x), f2bf(v.y), f2bf(v.z), f2bf(v.w)};
        *(ushort4*)(orow + c4 * 4) = o;
    }
    if (threadIdx.x < RANK) {
        float t = T[row * RANK + threadIdx.x];
        u16 hi = f2bf(t);
        orow[DIM + threadIdx.x] = hi;
        orow[DIM + RANK + threadIdx.x] = f2bf(t - bf2f(hi));
    }
}

// write T hi/lo into an existing bf16 [row][KE] buffer (o_ext)
__global__ __launch_bounds__(256) void pack_t_kernel(
    const float* __restrict__ T, u16* __restrict__ out)
{
    int idx = blockIdx.x * 256 + threadIdx.x;
    int row = idx >> 4, r = idx & 15;
    float t = T[idx];
    u16 hi = f2bf(t);
    out[(size_t)row * KE + DIM + r] = hi;
    out[(size_t)row * KE + DIM + RANK + r] = f2bf(t - bf2f(hi));
}

// ---------------------------------------------------------------------------
// bf16 MFMA GEMM: C = A @ W^T + bias.  A:[M][K], W:[N][K] bf16 (K=KE includes
// the folded LoRA columns). 128x128 tile, BK=32, global_load_lds width-16
// staging with XOR k-chunk swizzle. 1D grid with GROUP_M=8 L2 swizzle.
// SCATTER=1: write qkv workspace [3][NH][L][HD] fp32; SCATTER=0: [M][N] fp32.
// ---------------------------------------------------------------------------
template<int SCATTER>
__global__ __launch_bounds__(256) void gemm_mfma_kernel(
    const u16* __restrict__ A, const u16* __restrict__ W,
    const float* __restrict__ bias, float* __restrict__ C,
    int M, int N, int K)
{
    __shared__ __align__(16) u16 a_s[128 * 32];
    __shared__ __align__(16) u16 b_s[128 * 32];

    int tid = threadIdx.x;
    int wave = tid >> 6, lane = tid & 63;
    int quad = lane >> 4, l15 = lane & 15;
    int wm = wave >> 1, wn = wave & 1;

    // GROUP_M-swizzled block mapping for L2 locality
    int num_n = N >> 7, num_m = M >> 7;
    const int GM = 8;
    int stripe = GM * num_n;
    int group = blockIdx.x / stripe;
    int rem = blockIdx.x - group * stripe;
    int gm = num_m - group * GM; if (gm > GM) gm = GM;
    int bm = (group * GM + rem % gm) << 7;
    int bn = (rem / gm) << 7;

    const u16* ga[2]; const u16* gb[2];
    #pragma unroll
    for (int e = 0; e < 2; e++) {
        int r = wave * 32 + e * 16 + (lane >> 2);
        int g = (lane & 3) ^ ((r >> 1) & 3);
        ga[e] = A + (size_t)(bm + r) * K + g * 8;
        gb[e] = W + (size_t)(bn + r) * K + g * 8;
    }
    u16* lA[2] = { &a_s[(wave * 32 + 0) * 32], &a_s[(wave * 32 + 16) * 32] };
    u16* lB[2] = { &b_s[(wave * 32 + 0) * 32], &b_s[(wave * 32 + 16) * 32] };

    f32x4 acc[4][4];
    #pragma unroll
    for (int i = 0; i < 4; i++)
        #pragma unroll
        for (int j = 0; j < 4; j++) acc[i][j] = (f32x4){0.f, 0.f, 0.f, 0.f};

    int aoff[4], boff[4];
    #pragma unroll
    for (int i = 0; i < 4; i++) {
        int r = wm * 64 + i * 16 + l15;
        aoff[i] = r * 32 + (quad ^ ((r >> 1) & 3)) * 8;
        int rb = wn * 64 + i * 16 + l15;
        boff[i] = rb * 32 + (quad ^ ((rb >> 1) & 3)) * 8;
    }

    for (int k0 = 0; k0 < K; k0 += 32) {
        #pragma unroll
        for (int e = 0; e < 2; e++) {
            GLOBAL_TO_LDS16(ga[e] + k0, lA[e]);
            GLOBAL_TO_LDS16(gb[e] + k0, lB[e]);
        }
        __syncthreads();
        bf16x8 af[4], bf[4];
        #pragma unroll
        for (int i = 0; i < 4; i++) af[i] = *(const bf16x8*)&a_s[aoff[i]];
        #pragma unroll
        for (int j = 0; j < 4; j++) bf[j] = *(const bf16x8*)&b_s[boff[j]];
        #pragma unroll
        for (int i = 0; i < 4; i++)
            #pragma unroll
            for (int j = 0; j < 4; j++)
                acc[i][j] = __builtin_amdgcn_mfma_f32_16x16x32_bf16(af[i], bf[j], acc[i][j], 0, 0, 0);
        __syncthreads();
    }

    // epilogue: + bias, store (register-light)
    #pragma unroll
    for (int j = 0; j < 4; j++) {
        int col = bn + wn * 64 + j * 16 + l15;
        float bj = bias[col];
        int mq = 0, remc = col;
        if (SCATTER) {
            mq = (col >= 2 * DIM) ? 2 : (col >= DIM ? 1 : 0);
            remc = col - mq * DIM;
        }
        int hh = remc >> 7, dd = remc & 127;
        #pragma unroll
        for (int i = 0; i < 4; i++) {
            #pragma unroll
            for (int r = 0; r < 4; r++) {
                int row = bm + wm * 64 + i * 16 + quad * 4 + r;
                float val = acc[i][j][r] + bj;
                if (SCATTER)
                    C[(((size_t)(mq * NH + hh)) * L_SEQ + row) * HD + dd] = val;
                else
                    C[(size_t)row * N + col] = val;
            }
        }
    }
}

// ---------------------------------------------------------------------------
// RMSNorm + RoPE (q,k) / convert (v): fp32 qkv [3][NH][L][HD] -> bf16
// ---------------------------------------------------------------------------
__global__ __launch_bounds__(256) void rmsrope_kernel(
    const float* __restrict__ qkv, u16* __restrict__ qkv_bf,
    const float* __restrict__ pe,
    const float* __restrict__ q_scale, const float* __restrict__ k_scale)
{
    int wave = threadIdx.x >> 6;
    int lane = threadIdx.x & 63;
    int row = blockIdx.x * 4 + wave;               // h*L + l
    int which = blockIdx.y;                        // 0=q 1=k 2=v
    const float* base = qkv + ((size_t)which * NH * L_SEQ + row) * HD;
    u16* obase = qkv_bf + ((size_t)which * NH * L_SEQ + row) * HD;
    float2 t = *(const float2*)(base + 2 * lane);
    if (which == 2) {
        obase[2 * lane]     = f2bf(t.x);
        obase[2 * lane + 1] = f2bf(t.y);
        return;
    }
    const float* scale = which ? k_scale : q_scale;
    int l = row & (L_SEQ - 1);
    float ss = t.x * t.x + t.y * t.y;
    #pragma unroll
    for (int mm = 32; mm; mm >>= 1) ss += __shfl_xor(ss, mm);
    float rn = rsqrtf(ss * (1.0f / HD) + 1e-6f);
    float t0 = t.x * rn * scale[2 * lane];
    float t1 = t.y * rn * scale[2 * lane + 1];
    float4 p = *(const float4*)(pe + ((size_t)l * 64 + lane) * 4);
    obase[2 * lane]     = f2bf(p.x * t0 + p.y * t1);
    obase[2 * lane + 1] = f2bf(p.z * t0 + p.w * t1);
}

// ---------------------------------------------------------------------------
// bf16 MFMA flash attention (unchanged from round 2 except O pitch = KE).
// ---------------------------------------------------------------------------
__global__ __launch_bounds__(256) void attn_mfma_kernel(
    const u16* __restrict__ qkv_bf, u16* __restrict__ Og)
{
    __shared__ __align__(16) u16 k_s[64 * 128];
    __shared__ __align__(16) u16 v_s[128 * 72];
    __shared__ __align__(16) u16 p_s[4][16 * 72];

    int h = blockIdx.y;
    int q0 = blockIdx.x * 64;
    int tid = threadIdx.x;
    int wave = tid >> 6, lane = tid & 63;
    int quad = lane >> 4, l15 = lane & 15;
    const u16* qb = qkv_bf + (size_t)h * L_SEQ * HD;
    const u16* kb = qkv_bf + (size_t)(NH + h) * L_SEQ * HD;
    const u16* vb = qkv_bf + (size_t)(2 * NH + h) * L_SEQ * HD;

    bf16x8 aq[4];
    {
        const u16* qr = qb + (size_t)(q0 + wave * 16 + l15) * HD + quad * 8;
        #pragma unroll
        for (int ks = 0; ks < 4; ks++) aq[ks] = *(const bf16x8*)(qr + ks * 32);
    }

    f32x4 o_acc[8];
    #pragma unroll
    for (int n = 0; n < 8; n++) o_acc[n] = (f32x4){0.f, 0.f, 0.f, 0.f};
    float m_run[4] = {-1e30f, -1e30f, -1e30f, -1e30f};
    float l_run[4] = {0.f, 0.f, 0.f, 0.f};
    const float sc = 0.08838834764831845f * 1.4426950408889634f;

    const u16* gk[4];
    #pragma unroll
    for (int e = 0; e < 4; e++) {
        int r = wave * 16 + e * 4 + (lane >> 4);
        int g = l15 ^ (r & 15);
        gk[e] = kb + (size_t)r * HD + g * 8;
    }

    for (int kv0 = 0; kv0 < L_SEQ; kv0 += 64) {
        __syncthreads();
        #pragma unroll
        for (int e = 0; e < 4; e++)
            GLOBAL_TO_LDS16(gk[e] + (size_t)kv0 * HD, &k_s[(wave * 16 + e * 4) * 128]);
        {
            int r = tid >> 2;
            int c0 = (tid & 3) * 8;
            const u16* vr = vb + (size_t)(kv0 + r) * HD;
            #pragma unroll
            for (int it = 0; it < 4; it++) {
                int d0 = c0 + it * 32;
                uint4 v = *(const uint4*)(vr + d0);
                v_s[(d0 + 0) * 72 + r] = (u16)(v.x);
                v_s[(d0 + 1) * 72 + r] = (u16)(v.x >> 16);
                v_s[(d0 + 2) * 72 + r] = (u16)(v.y);
                v_s[(d0 + 3) * 72 + r] = (u16)(v.y >> 16);
                v_s[(d0 + 4) * 72 + r] = (u16)(v.z);
                v_s[(d0 + 5) * 72 + r] = (u16)(v.z >> 16);
                v_s[(d0 + 6) * 72 + r] = (u16)(v.w);
                v_s[(d0 + 7) * 72 + r] = (u16)(v.w >> 16);
            }
        }
        __syncthreads();

        f32x4 sacc[4];
        #pragma unroll
        for (int j = 0; j < 4; j++) sacc[j] = (f32x4){0.f, 0.f, 0.f, 0.f};
        #pragma unroll
        for (int ks = 0; ks < 4; ks++) {
            #pragma unroll
            for (int j = 0; j < 4; j++) {
                int n = j * 16 + l15;
                int slot = (ks * 4 + quad) ^ (n & 15);
                bf16x8 bk = *(const bf16x8*)&k_s[n * 128 + slot * 8];
                sacc[j] = __builtin_amdgcn_mfma_f32_16x16x32_bf16(aq[ks], bk, sacc[j], 0, 0, 0);
            }
        }

        float alpha[4];
        #pragma unroll
        for (int r = 0; r < 4; r++) {
            float rmax = fmaxf(fmaxf(sacc[0][r], sacc[1][r]), fmaxf(sacc[2][r], sacc[3][r]));
            #pragma unroll
            for (int mm = 8; mm; mm >>= 1) rmax = fmaxf(rmax, __shfl_xor(rmax, mm));
            float m_new = fmaxf(m_run[r], rmax);
            alpha[r] = exp2f((m_run[r] - m_new) * sc);
            m_run[r] = m_new;
            float ps = 0.f;
            #pragma unroll
            for (int j = 0; j < 4; j++) {
                float p = exp2f((sacc[j][r] - m_new) * sc);
                sacc[j][r] = p;
                ps += p;
            }
            #pragma unroll
            for (int mm = 8; mm; mm >>= 1) ps += __shfl_xor(ps, mm);
            l_run[r] = l_run[r] * alpha[r] + ps;
        }

        #pragma unroll
        for (int j = 0; j < 4; j++)
            #pragma unroll
            for (int r = 0; r < 4; r++)
                p_s[wave][(quad * 4 + r) * 72 + j * 16 + l15] = f2bf(sacc[j][r]);
        bf16x8 ap[2];
        #pragma unroll
        for (int ks = 0; ks < 2; ks++)
            ap[ks] = *(const bf16x8*)&p_s[wave][l15 * 72 + ks * 32 + quad * 8];

        #pragma unroll
        for (int n = 0; n < 8; n++)
            #pragma unroll
            for (int r = 0; r < 4; r++) o_acc[n][r] *= alpha[r];
        #pragma unroll
        for (int ks = 0; ks < 2; ks++) {
            #pragma unroll
            for (int n = 0; n < 8; n++) {
                bf16x8 bv = *(const bf16x8*)&v_s[(n * 16 + l15) * 72 + ks * 32 + quad * 8];
                o_acc[n] = __builtin_amdgcn_mfma_f32_16x16x32_bf16(ap[ks], bv, o_acc[n], 0, 0, 0);
            }
        }
    }

    #pragma unroll
    for (int r = 0; r < 4; r++) {
        float inv = 1.f / l_run[r];
        int row = q0 + wave * 16 + quad * 4 + r;
        u16* orow = Og + (size_t)row * KE + h * HD;
        #pragma unroll
        for (int n = 0; n < 8; n++)
            orow[n * 16 + l15] = f2bf(o_acc[n][r] * inv);
    }
}

// ---------------------------------------------------------------------------
extern "C" void kernel_launch(void* const* d_in, const int* in_sizes, int n_in,
                              void* d_out, int out_size, void* d_ws, size_t ws_size,
                              hipStream_t stream)
{
    const float* x         = (const float*)d_in[0];
    const float* pe        = (const float*)d_in[1];
    const float* qkv_w     = (const float*)d_in[2];
    const float* qkv_b     = (const float*)d_in[3];
    const float* proj_w    = (const float*)d_in[4];
    const float* proj_b    = (const float*)d_in[5];
    const float* qkv_down  = (const float*)d_in[6];
    const float* qkv_up    = (const float*)d_in[7];
    const float* proj_down = (const float*)d_in[8];
    const float* proj_up   = (const float*)d_in[9];
    const float* q_scale   = (const float*)d_in[10];
    const float* k_scale   = (const float*)d_in[11];
    float* out = (float*)d_out;

    const size_t QKV_ELEMS = (size_t)3 * NH * L_SEQ * HD;
    char* w = (char*)d_ws;
    float* qkv_f  = (float*)w;  w += QKV_ELEMS * 4;                  // 75.5 MB
    u16*   qkv_bf = (u16*)w;    w += QKV_ELEMS * 2;                  // 37.7 MB
    u16*   x_ext  = (u16*)w;    w += (size_t)L_SEQ * KE * 2;         // 12.7 MB
    u16*   wq_ext = (u16*)w;    w += (size_t)N_QKV * KE * 2;         // 57.2 MB
    u16*   wp_ext = (u16*)w;    w += (size_t)DIM * KE * 2;           // 19.1 MB
    u16*   o_ext  = (u16*)w;    w += (size_t)L_SEQ * KE * 2;         // 12.7 MB
    float* t1     = (float*)w;  w += (size_t)L_SEQ * RANK * 4;
    float* t2     = (float*)w;

    pack_w_kernel<<<N_QKV, 256, 0, stream>>>(qkv_w, qkv_up, wq_ext);
    pack_w_kernel<<<DIM, 256, 0, stream>>>(proj_w, proj_up, wp_ext);
    lora_down_kernel<<<L_SEQ, 256, 0, stream>>>(x, qkv_down, t1);
    pack_x_kernel<<<L_SEQ, 256, 0, stream>>>(x, t1, x_ext);

    gemm_mfma_kernel<1><<<(N_QKV / 128) * (L_SEQ / 128), 256, 0, stream>>>(
        x_ext, wq_ext, qkv_b, qkv_f, L_SEQ, N_QKV, KE);
    rmsrope_kernel<<<dim3(NH * L_SEQ / 4, 3), 256, 0, stream>>>(
        qkv_f, qkv_bf, pe, q_scale, k_scale);
    attn_mfma_kernel<<<dim3(L_SEQ / 64, NH), 256, 0, stream>>>(qkv_bf, o_ext);
    lora_down_bf_kernel<<<L_SEQ, 256, 0, stream>>>(o_ext, proj_down, t2, KE);
    pack_t_kernel<<<L_SEQ * RANK / 256, 256, 0, stream>>>(t2, o_ext);
    gemm_mfma_kernel<0><<<(DIM / 128) * (L_SEQ / 128), 256, 0, stream>>>(
        o_ext, wp_ext, proj_b, out, L_SEQ, DIM, KE);
}

// Round 4
// 762.613 us; speedup vs baseline: 4.3449x; 1.1954x over previous
//
#include <hip/hip_runtime.h>
#include <math.h>

#define L_SEQ 2048
#define DIM   3072
#define NH    24
#define HD    128
#define RANK  16
#define N_QKV 9216
#define KE    3136   // DIM + 16 (T_hi|Up) + 16 (T_lo|Up) + 32 zero pad; 64 | KE

typedef __attribute__((ext_vector_type(8))) short bf16x8;
typedef __attribute__((ext_vector_type(4))) float f32x4;
typedef unsigned short u16;
typedef unsigned int u32;

__device__ __forceinline__ u16 f2bf(float f) {
    union { float f; u32 u; } v; v.f = f;
    return (u16)((v.u + 0x7fffu + ((v.u >> 16) & 1u)) >> 16);
}
__device__ __forceinline__ float bf2f(u16 h) {
    union { u32 u; float f; } v; v.u = ((u32)h) << 16; return v.f;
}

#define GLOBAL_TO_LDS16(gp, lp) \
  __builtin_amdgcn_global_load_lds((const __attribute__((address_space(1))) u32*)(gp), \
                                   (__attribute__((address_space(3))) u32*)(lp), 16, 0, 0)

// ---------------------------------------------------------------------------
// pe [1,1,L,64,2,2] -> pe2 [L][64] (cos, sin)
// ---------------------------------------------------------------------------
__global__ __launch_bounds__(64) void pack_pe_kernel(
    const float* __restrict__ pe, float2* __restrict__ pe2)
{
    int l = blockIdx.x, i = threadIdx.x;
    int base = l * 256 + i * 4;
    float2 cs; cs.x = pe[base]; cs.y = pe[base + 2];
    pe2[l * 64 + i] = cs;
}

// ---------------------------------------------------------------------------
// T[l][r] = dot(X[l,:DIM], W[r,:DIM])  rank-16 LoRA down (fp32 X)
// ---------------------------------------------------------------------------
__global__ __launch_bounds__(256) void lora_down_kernel(
    const float* __restrict__ X, const float* __restrict__ W, float* __restrict__ T)
{
    int l = blockIdx.x;
    int r = threadIdx.x >> 4;
    int lane = threadIdx.x & 15;
    const float* xr = X + (size_t)l * DIM;
    const float* wr = W + (size_t)r * DIM;
    float s = 0.f;
    for (int k = lane; k < DIM; k += 16) s = fmaf(xr[k], wr[k], s);
    #pragma unroll
    for (int mm = 8; mm; mm >>= 1) s += __shfl_xor(s, mm);
    if (lane == 0) T[l * RANK + r] = s;
}

// bf16-X variant with row pitch (for o_ext)
__global__ __launch_bounds__(256) void lora_down_bf_kernel(
    const u16* __restrict__ X, const float* __restrict__ W, float* __restrict__ T, int pitch)
{
    int l = blockIdx.x;
    int r = threadIdx.x >> 4;
    int lane = threadIdx.x & 15;
    const u16* xr = X + (size_t)l * pitch;
    const float* wr = W + (size_t)r * DIM;
    float s = 0.f;
    for (int k = lane; k < DIM; k += 16) s = fmaf(bf2f(xr[k]), wr[k], s);
    #pragma unroll
    for (int mm = 8; mm; mm >>= 1) s += __shfl_xor(s, mm);
    if (lane == 0) T[l * RANK + r] = s;
}

// ---------------------------------------------------------------------------
// pack weights: [0:DIM)=bf16(W), [DIM,DIM+16)=Up, [DIM+16,DIM+32)=Up, pad=0
// ---------------------------------------------------------------------------
__global__ __launch_bounds__(256) void pack_w_kernel(
    const float* __restrict__ W, const float* __restrict__ Up, u16* __restrict__ out)
{
    int row = blockIdx.x;
    const float* wr = W + (size_t)row * DIM;
    u16* orow = out + (size_t)row * KE;
    #pragma unroll
    for (int it = 0; it < 3; it++) {
        int c4 = threadIdx.x + it * 256;
        float4 v = ((const float4*)wr)[c4];
        ushort4 o = {f2bf(v.x), f2bf(v.y), f2bf(v.z), f2bf(v.w)};
        *(ushort4*)(orow + c4 * 4) = o;
    }
    int t = threadIdx.x;
    if (t < RANK) {
        u16 b = f2bf(Up[row * RANK + t]);
        orow[DIM + t] = b;
        orow[DIM + RANK + t] = b;
    } else if (t >= 32 && t < 64) {
        orow[DIM + t] = 0;
    }
}

// pack activations: [0:DIM)=bf16(X), then T hi/lo, pad=0
__global__ __launch_bounds__(256) void pack_x_kernel(
    const float* __restrict__ X, const float* __restrict__ T, u16* __restrict__ out)
{
    int row = blockIdx.x;
    const float* xr = X + (size_t)row * DIM;
    u16* orow = out + (size_t)row * KE;
    #pragma unroll
    for (int it = 0; it < 3; it++) {
        int c4 = threadIdx.x + it * 256;
        float4 v = ((const float4*)xr)[c4];
        ushort4 o = {f2bf(v.x), f2bf(v.y), f2bf(v.z), f2bf(v.w)};
        *(ushort4*)(orow + c4 * 4) = o;
    }
    int t = threadIdx.x;
    if (t < RANK) {
        float tv = T[row * RANK + t];
        u16 hi = f2bf(tv);
        orow[DIM + t] = hi;
        orow[DIM + RANK + t] = f2bf(tv - bf2f(hi));
    } else if (t >= 32 && t < 64) {
        orow[DIM + t] = 0;
    }
}

// write T hi/lo + zero pad into existing bf16 [row][KE] buffer (o_ext)
__global__ __launch_bounds__(64) void pack_t_kernel(
    const float* __restrict__ T, u16* __restrict__ out)
{
    int row = blockIdx.x, t = threadIdx.x;
    u16* orow = out + (size_t)row * KE;
    if (t < RANK) {
        float tv = T[row * RANK + t];
        u16 hi = f2bf(tv);
        orow[DIM + t] = hi;
        orow[DIM + RANK + t] = f2bf(tv - bf2f(hi));
    } else if (t >= 32) {
        orow[DIM + t] = 0;
    }
}

// ---------------------------------------------------------------------------
// bf16 MFMA GEMM, 128x128 tile, BK=64 (32 KB LDS), LoRA folded into K.
// MODE 0: C = A@W^T + bias -> fp32 [M][N]  (proj)
// MODE 1: qkv with fused RMSNorm+RoPE epilogue:
//   q,k -> bf16 [2][NH][L][HD]; v -> bf16 [NH][HD][L] with kv-chunk XOR
//   swizzle baked into the global layout (for conflict-free attn staging).
// ---------------------------------------------------------------------------
template<int MODE>
__global__ __launch_bounds__(256) void gemm_mfma_kernel(
    const u16* __restrict__ A, const u16* __restrict__ W,
    const float* __restrict__ bias,
    float* __restrict__ Cf,
    u16* __restrict__ qkbf, u16* __restrict__ vT,
    const float2* __restrict__ pe2,
    const float* __restrict__ q_scale, const float* __restrict__ k_scale,
    int M, int N, int K)
{
    __shared__ __align__(16) u16 a_s[128 * 64];   // 16 KB
    __shared__ __align__(16) u16 b_s[128 * 64];   // 16 KB

    int tid = threadIdx.x;
    int wave = tid >> 6, lane = tid & 63;
    int quad = lane >> 4, l15 = lane & 15;
    int wm = wave >> 1, wn = wave & 1;

    // GROUP_M-swizzled block mapping
    int num_n = N >> 7, num_m = M >> 7;
    const int GM = 8;
    int stripe = GM * num_n;
    int group = blockIdx.x / stripe;
    int rem = blockIdx.x - group * stripe;
    int gm = num_m - group * GM; if (gm > GM) gm = GM;
    int bm = (group * GM + rem % gm) << 7;
    int bn = (rem / gm) << 7;

    // staging: 4 issues per matrix; 32 rows x 128 B per issue; chunk XOR swizzle
    const u16* ga[4]; const u16* gb[4];
    u16 *lA[4], *lB[4];
    #pragma unroll
    for (int e = 0; e < 4; e++) {
        int r = e * 32 + (tid >> 3);
        int g = (tid & 7) ^ (r & 7);
        ga[e] = A + (size_t)(bm + r) * K + g * 8;
        gb[e] = W + (size_t)(bn + r) * K + g * 8;
        lA[e] = &a_s[(e * 32 + wave * 8) * 64];
        lB[e] = &b_s[(e * 32 + wave * 8) * 64];
    }

    f32x4 acc[4][4];
    #pragma unroll
    for (int i = 0; i < 4; i++)
        #pragma unroll
        for (int j = 0; j < 4; j++) acc[i][j] = (f32x4){0.f, 0.f, 0.f, 0.f};

    int abase[4], bbase[4], co[2];
    #pragma unroll
    for (int i = 0; i < 4; i++) {
        abase[i] = (wm * 64 + i * 16 + l15) * 64;
        bbase[i] = (wn * 64 + i * 16 + l15) * 64;
    }
    #pragma unroll
    for (int ks = 0; ks < 2; ks++) co[ks] = ((ks * 4 + quad) ^ (l15 & 7)) * 8;

    for (int k0 = 0; k0 < K; k0 += 64) {
        #pragma unroll
        for (int e = 0; e < 4; e++) {
            GLOBAL_TO_LDS16(ga[e] + k0, lA[e]);
            GLOBAL_TO_LDS16(gb[e] + k0, lB[e]);
        }
        __syncthreads();
        #pragma unroll
        for (int ks = 0; ks < 2; ks++) {
            bf16x8 af[4], bf[4];
            #pragma unroll
            for (int i = 0; i < 4; i++) af[i] = *(const bf16x8*)&a_s[abase[i] + co[ks]];
            #pragma unroll
            for (int j = 0; j < 4; j++) bf[j] = *(const bf16x8*)&b_s[bbase[j] + co[ks]];
            #pragma unroll
            for (int i = 0; i < 4; i++)
                #pragma unroll
                for (int j = 0; j < 4; j++)
                    acc[i][j] = __builtin_amdgcn_mfma_f32_16x16x32_bf16(af[i], bf[j], acc[i][j], 0, 0, 0);
        }
        __syncthreads();
    }

    if (MODE == 0) {
        #pragma unroll
        for (int j = 0; j < 4; j++) {
            int col = bn + wn * 64 + j * 16 + l15;
            float bj = bias[col];
            #pragma unroll
            for (int i = 0; i < 4; i++)
                #pragma unroll
                for (int r = 0; r < 4; r++) {
                    int row = bm + wm * 64 + i * 16 + quad * 4 + r;
                    Cf[(size_t)row * N + col] = acc[i][j][r] + bj;
                }
        }
        return;
    }

    // ---- MODE 1: fused qkv epilogue ----
    int tn = bn >> 7;
    int mq = (tn >= 48) ? 2 : (tn >= 24 ? 1 : 0);
    int h = tn - mq * 24;

    #pragma unroll
    for (int j = 0; j < 4; j++) {
        float bj = bias[bn + wn * 64 + j * 16 + l15];
        #pragma unroll
        for (int i = 0; i < 4; i++)
            #pragma unroll
            for (int r = 0; r < 4; r++) acc[i][j][r] += bj;
    }

    if (mq == 2) {
        // V: store transposed [h][d][L] with chunk swizzle baked in
        #pragma unroll
        for (int j = 0; j < 4; j++) {
            int d = wn * 64 + j * 16 + l15;
            u16* vrow = vT + ((size_t)h * HD + d) * L_SEQ;
            #pragma unroll
            for (int i = 0; i < 4; i++)
                #pragma unroll
                for (int r = 0; r < 4; r++) {
                    int kv = bm + wm * 64 + i * 16 + quad * 4 + r;
                    int slot = ((kv >> 3) & 7) ^ (d & 7);
                    int colp = (kv & ~63) + slot * 8 + (kv & 7);
                    vrow[colp] = f2bf(acc[i][j][r]);
                }
        }
    } else {
        // per-row sum of squares over this wave's 64 cols
        float ssp[4][4];
        #pragma unroll
        for (int i = 0; i < 4; i++)
            #pragma unroll
            for (int r = 0; r < 4; r++) {
                float s = 0.f;
                #pragma unroll
                for (int j = 0; j < 4; j++) s = fmaf(acc[i][j][r], acc[i][j][r], s);
                #pragma unroll
                for (int mm = 8; mm; mm >>= 1) s += __shfl_xor(s, mm);
                ssp[i][r] = s;
            }
        // combine the two wn-halves via LDS (a_s reads all done: loop ends with barrier)
        float* ss_s = (float*)a_s;
        if (l15 == 0) {
            #pragma unroll
            for (int i = 0; i < 4; i++)
                *(float4*)&ss_s[wn * 128 + wm * 64 + i * 16 + quad * 4] =
                    make_float4(ssp[i][0], ssp[i][1], ssp[i][2], ssp[i][3]);
        }
        __syncthreads();
        float rfac[4][4];
        #pragma unroll
        for (int i = 0; i < 4; i++) {
            float4 s0 = *(const float4*)&ss_s[wm * 64 + i * 16 + quad * 4];
            float4 s1 = *(const float4*)&ss_s[128 + wm * 64 + i * 16 + quad * 4];
            rfac[i][0] = rsqrtf((s0.x + s1.x) * (1.f / HD) + 1e-6f);
            rfac[i][1] = rsqrtf((s0.y + s1.y) * (1.f / HD) + 1e-6f);
            rfac[i][2] = rsqrtf((s0.z + s1.z) * (1.f / HD) + 1e-6f);
            rfac[i][3] = rsqrtf((s0.w + s1.w) * (1.f / HD) + 1e-6f);
        }
        const float* scale = mq ? k_scale : q_scale;
        float sgn = (l15 & 1) ? 1.f : -1.f;
        u16* obase = qkbf + (size_t)(mq * NH + h) * L_SEQ * HD;
        #pragma unroll
        for (int j = 0; j < 4; j++) {
            int d = wn * 64 + j * 16 + l15;
            float sd = scale[d];
            #pragma unroll
            for (int i = 0; i < 4; i++)
                #pragma unroll
                for (int r = 0; r < 4; r++) {
                    int row = bm + wm * 64 + i * 16 + quad * 4 + r;
                    float t = acc[i][j][r] * rfac[i][r] * sd;
                    float tp = __shfl_xor(t, 1);
                    float2 cs = pe2[row * 64 + (d >> 1)];
                    float o = fmaf(cs.x, t, sgn * cs.y * tp);
                    obase[(size_t)row * HD + d] = f2bf(o);
                }
        }
    }
}

// ---------------------------------------------------------------------------
// bf16 MFMA flash attention. V arrives pre-transposed+swizzled [h][d][L];
// both K and V staged via global_load_lds (no in-kernel transpose).
// ---------------------------------------------------------------------------
__global__ __launch_bounds__(256) void attn_mfma_kernel(
    const u16* __restrict__ qk_bf, const u16* __restrict__ vT, u16* __restrict__ Og)
{
    __shared__ __align__(16) u16 k_s[64 * 128];    // 16 KB, [kv][d] 16-chunk swizzled
    __shared__ __align__(16) u16 v_s[128 * 64];    // 16 KB, [d][kv] 8-chunk swizzled
    __shared__ __align__(16) u16 p_s[4][16 * 72];  // 9 KB per-wave P

    int h = blockIdx.y;
    int q0 = blockIdx.x * 64;
    int tid = threadIdx.x;
    int wave = tid >> 6, lane = tid & 63;
    int quad = lane >> 4, l15 = lane & 15;
    const u16* qb = qk_bf + (size_t)h * L_SEQ * HD;
    const u16* kb = qk_bf + (size_t)(NH + h) * L_SEQ * HD;
    const u16* vTh = vT + (size_t)h * HD * L_SEQ;

    bf16x8 aq[4];
    {
        const u16* qr = qb + (size_t)(q0 + wave * 16 + l15) * HD + quad * 8;
        #pragma unroll
        for (int ks = 0; ks < 4; ks++) aq[ks] = *(const bf16x8*)(qr + ks * 32);
    }

    f32x4 o_acc[8];
    #pragma unroll
    for (int n = 0; n < 8; n++) o_acc[n] = (f32x4){0.f, 0.f, 0.f, 0.f};
    float m_run[4] = {-1e30f, -1e30f, -1e30f, -1e30f};
    float l_run[4] = {0.f, 0.f, 0.f, 0.f};
    const float sc = 0.08838834764831845f * 1.4426950408889634f;

    // K staging (rows of 256 B, 16-chunk swizzle)
    const u16* gk[4];
    #pragma unroll
    for (int e = 0; e < 4; e++) {
        int r = wave * 16 + e * 4 + (lane >> 4);
        int g = l15 ^ (r & 15);
        gk[e] = kb + (size_t)r * HD + g * 8;
    }
    // V staging (rows of 128 B from pre-swizzled global, linear copy)
    const u16* gv[4];
    #pragma unroll
    for (int e = 0; e < 4; e++) {
        int d = wave * 32 + e * 8 + (lane >> 3);
        gv[e] = vTh + (size_t)d * L_SEQ + (lane & 7) * 8;
    }
    int vco[2];
    #pragma unroll
    for (int ks = 0; ks < 2; ks++) vco[ks] = ((ks * 4 + quad) ^ (l15 & 7)) * 8;

    for (int kv0 = 0; kv0 < L_SEQ; kv0 += 64) {
        __syncthreads();
        #pragma unroll
        for (int e = 0; e < 4; e++) {
            GLOBAL_TO_LDS16(gk[e] + (size_t)kv0 * HD, &k_s[(wave * 16 + e * 4) * 128]);
            GLOBAL_TO_LDS16(gv[e] + kv0, &v_s[(wave * 32 + e * 8) * 64]);
        }
        __syncthreads();

        // S = Q K^T
        f32x4 sacc[4];
        #pragma unroll
        for (int j = 0; j < 4; j++) sacc[j] = (f32x4){0.f, 0.f, 0.f, 0.f};
        #pragma unroll
        for (int ks = 0; ks < 4; ks++) {
            #pragma unroll
            for (int j = 0; j < 4; j++) {
                int n = j * 16 + l15;
                int slot = (ks * 4 + quad) ^ (n & 15);
                bf16x8 bk = *(const bf16x8*)&k_s[n * 128 + slot * 8];
                sacc[j] = __builtin_amdgcn_mfma_f32_16x16x32_bf16(aq[ks], bk, sacc[j], 0, 0, 0);
            }
        }

        // online softmax
        float alpha[4];
        #pragma unroll
        for (int r = 0; r < 4; r++) {
            float rmax = fmaxf(fmaxf(sacc[0][r], sacc[1][r]), fmaxf(sacc[2][r], sacc[3][r]));
            #pragma unroll
            for (int mm = 8; mm; mm >>= 1) rmax = fmaxf(rmax, __shfl_xor(rmax, mm));
            float m_new = fmaxf(m_run[r], rmax);
            alpha[r] = exp2f((m_run[r] - m_new) * sc);
            m_run[r] = m_new;
            float ps = 0.f;
            #pragma unroll
            for (int j = 0; j < 4; j++) {
                float p = exp2f((sacc[j][r] - m_new) * sc);
                sacc[j][r] = p;
                ps += p;
            }
            #pragma unroll
            for (int mm = 8; mm; mm >>= 1) ps += __shfl_xor(ps, mm);
            l_run[r] = l_run[r] * alpha[r] + ps;
        }

        // P: C-layout -> A-layout via per-wave LDS
        #pragma unroll
        for (int j = 0; j < 4; j++)
            #pragma unroll
            for (int r = 0; r < 4; r++)
                p_s[wave][(quad * 4 + r) * 72 + j * 16 + l15] = f2bf(sacc[j][r]);
        bf16x8 ap[2];
        #pragma unroll
        for (int ks = 0; ks < 2; ks++)
            ap[ks] = *(const bf16x8*)&p_s[wave][l15 * 72 + ks * 32 + quad * 8];

        #pragma unroll
        for (int n = 0; n < 8; n++)
            #pragma unroll
            for (int r = 0; r < 4; r++) o_acc[n][r] *= alpha[r];
        #pragma unroll
        for (int ks = 0; ks < 2; ks++) {
            #pragma unroll
            for (int n = 0; n < 8; n++) {
                bf16x8 bv = *(const bf16x8*)&v_s[(n * 16 + l15) * 64 + vco[ks]];
                o_acc[n] = __builtin_amdgcn_mfma_f32_16x16x32_bf16(ap[ks], bv, o_acc[n], 0, 0, 0);
            }
        }
    }

    #pragma unroll
    for (int r = 0; r < 4; r++) {
        float inv = 1.f / l_run[r];
        int row = q0 + wave * 16 + quad * 4 + r;
        u16* orow = Og + (size_t)row * KE + h * HD;
        #pragma unroll
        for (int n = 0; n < 8; n++)
            orow[n * 16 + l15] = f2bf(o_acc[n][r] * inv);
    }
}

// ---------------------------------------------------------------------------
extern "C" void kernel_launch(void* const* d_in, const int* in_sizes, int n_in,
                              void* d_out, int out_size, void* d_ws, size_t ws_size,
                              hipStream_t stream)
{
    const float* x         = (const float*)d_in[0];
    const float* pe        = (const float*)d_in[1];
    const float* qkv_w     = (const float*)d_in[2];
    const float* qkv_b     = (const float*)d_in[3];
    const float* proj_w    = (const float*)d_in[4];
    const float* proj_b    = (const float*)d_in[5];
    const float* qkv_down  = (const float*)d_in[6];
    const float* qkv_up    = (const float*)d_in[7];
    const float* proj_down = (const float*)d_in[8];
    const float* proj_up   = (const float*)d_in[9];
    const float* q_scale   = (const float*)d_in[10];
    const float* k_scale   = (const float*)d_in[11];
    float* out = (float*)d_out;

    char* w = (char*)d_ws;
    u16*   qk_bf  = (u16*)w;    w += (size_t)2 * NH * L_SEQ * HD * 2;  // 25.2 MB
    u16*   vT_bf  = (u16*)w;    w += (size_t)NH * HD * L_SEQ * 2;      // 12.6 MB
    u16*   x_ext  = (u16*)w;    w += (size_t)L_SEQ * KE * 2;           // 12.8 MB
    u16*   wq_ext = (u16*)w;    w += (size_t)N_QKV * KE * 2;           // 57.8 MB
    u16*   wp_ext = (u16*)w;    w += (size_t)DIM * KE * 2;             // 19.3 MB
    u16*   o_ext  = (u16*)w;    w += (size_t)L_SEQ * KE * 2;           // 12.8 MB
    float2* pe2   = (float2*)w; w += (size_t)L_SEQ * 64 * sizeof(float2);
    float* t1     = (float*)w;  w += (size_t)L_SEQ * RANK * 4;
    float* t2     = (float*)w;

    pack_pe_kernel<<<L_SEQ, 64, 0, stream>>>(pe, pe2);
    pack_w_kernel<<<N_QKV, 256, 0, stream>>>(qkv_w, qkv_up, wq_ext);
    pack_w_kernel<<<DIM, 256, 0, stream>>>(proj_w, proj_up, wp_ext);
    lora_down_kernel<<<L_SEQ, 256, 0, stream>>>(x, qkv_down, t1);
    pack_x_kernel<<<L_SEQ, 256, 0, stream>>>(x, t1, x_ext);

    gemm_mfma_kernel<1><<<(N_QKV / 128) * (L_SEQ / 128), 256, 0, stream>>>(
        x_ext, wq_ext, qkv_b, nullptr, qk_bf, vT_bf, pe2, q_scale, k_scale,
        L_SEQ, N_QKV, KE);
    attn_mfma_kernel<<<dim3(L_SEQ / 64, NH), 256, 0, stream>>>(qk_bf, vT_bf, o_ext);
    lora_down_bf_kernel<<<L_SEQ, 256, 0, stream>>>(o_ext, proj_down, t2, KE);
    pack_t_kernel<<<L_SEQ, 64, 0, stream>>>(t2, o_ext);
    gemm_mfma_kernel<0><<<(DIM / 128) * (L_SEQ / 128), 256, 0, stream>>>(
        o_ext, wp_ext, proj_b, out, nullptr, nullptr, nullptr, nullptr, nullptr,
        L_SEQ, DIM, KE);
}

// Round 5
// 708.755 us; speedup vs baseline: 4.6751x; 1.0760x over previous
//
#include <hip/hip_runtime.h>
#include <math.h>

#define L_SEQ 2048
#define DIM   3072
#define NH    24
#define HD    128
#define RANK  16
#define N_QKV 9216
#define KE    3136   // DIM + 16 (T_hi|Up) + 16 (T_lo|Up) + 32 zero pad; 64 | KE

typedef __attribute__((ext_vector_type(8))) short bf16x8;
typedef __attribute__((ext_vector_type(4))) float f32x4;
typedef unsigned short u16;
typedef unsigned int u32;

__device__ __forceinline__ u16 f2bf(float f) {
    union { float f; u32 u; } v; v.f = f;
    return (u16)((v.u + 0x7fffu + ((v.u >> 16) & 1u)) >> 16);
}
__device__ __forceinline__ float bf2f(u16 h) {
    union { u32 u; float f; } v; v.u = ((u32)h) << 16; return v.f;
}

#define GLOBAL_TO_LDS16(gp, lp) \
  __builtin_amdgcn_global_load_lds((const __attribute__((address_space(1))) u32*)(gp), \
                                   (__attribute__((address_space(3))) u32*)(lp), 16, 0, 0)

// ---------------------------------------------------------------------------
// pe [1,1,L,64,2,2] -> pe2 [L][64] (cos, sin)
// ---------------------------------------------------------------------------
__global__ __launch_bounds__(64) void pack_pe_kernel(
    const float* __restrict__ pe, float2* __restrict__ pe2)
{
    int l = blockIdx.x, i = threadIdx.x;
    int base = l * 256 + i * 4;
    float2 cs; cs.x = pe[base]; cs.y = pe[base + 2];
    pe2[l * 64 + i] = cs;
}

// ---------------------------------------------------------------------------
// T[l][r] = dot(X[l,:DIM], W[r,:DIM])  rank-16 LoRA down (fp32 X)
// ---------------------------------------------------------------------------
__global__ __launch_bounds__(256) void lora_down_kernel(
    const float* __restrict__ X, const float* __restrict__ W, float* __restrict__ T)
{
    int l = blockIdx.x;
    int r = threadIdx.x >> 4;
    int lane = threadIdx.x & 15;
    const float* xr = X + (size_t)l * DIM;
    const float* wr = W + (size_t)r * DIM;
    float s = 0.f;
    for (int k = lane; k < DIM; k += 16) s = fmaf(xr[k], wr[k], s);
    #pragma unroll
    for (int mm = 8; mm; mm >>= 1) s += __shfl_xor(s, mm);
    if (lane == 0) T[l * RANK + r] = s;
}

// bf16-X variant with row pitch (for o_ext)
__global__ __launch_bounds__(256) void lora_down_bf_kernel(
    const u16* __restrict__ X, const float* __restrict__ W, float* __restrict__ T, int pitch)
{
    int l = blockIdx.x;
    int r = threadIdx.x >> 4;
    int lane = threadIdx.x & 15;
    const u16* xr = X + (size_t)l * pitch;
    const float* wr = W + (size_t)r * DIM;
    float s = 0.f;
    for (int k = lane; k < DIM; k += 16) s = fmaf(bf2f(xr[k]), wr[k], s);
    #pragma unroll
    for (int mm = 8; mm; mm >>= 1) s += __shfl_xor(s, mm);
    if (lane == 0) T[l * RANK + r] = s;
}

// ---------------------------------------------------------------------------
// pack weights: [0:DIM)=bf16(W), [DIM,DIM+16)=Up, [DIM+16,DIM+32)=Up, pad=0
// ---------------------------------------------------------------------------
__global__ __launch_bounds__(256) void pack_w_kernel(
    const float* __restrict__ W, const float* __restrict__ Up, u16* __restrict__ out)
{
    int row = blockIdx.x;
    const float* wr = W + (size_t)row * DIM;
    u16* orow = out + (size_t)row * KE;
    #pragma unroll
    for (int it = 0; it < 3; it++) {
        int c4 = threadIdx.x + it * 256;
        float4 v = ((const float4*)wr)[c4];
        ushort4 o = {f2bf(v.x), f2bf(v.y), f2bf(v.z), f2bf(v.w)};
        *(ushort4*)(orow + c4 * 4) = o;
    }
    int t = threadIdx.x;
    if (t < RANK) {
        u16 b = f2bf(Up[row * RANK + t]);
        orow[DIM + t] = b;
        orow[DIM + RANK + t] = b;
    } else if (t >= 32 && t < 64) {
        orow[DIM + t] = 0;
    }
}

// pack activations: [0:DIM)=bf16(X), then T hi/lo, pad=0
__global__ __launch_bounds__(256) void pack_x_kernel(
    const float* __restrict__ X, const float* __restrict__ T, u16* __restrict__ out)
{
    int row = blockIdx.x;
    const float* xr = X + (size_t)row * DIM;
    u16* orow = out + (size_t)row * KE;
    #pragma unroll
    for (int it = 0; it < 3; it++) {
        int c4 = threadIdx.x + it * 256;
        float4 v = ((const float4*)xr)[c4];
        ushort4 o = {f2bf(v.x), f2bf(v.y), f2bf(v.z), f2bf(v.w)};
        *(ushort4*)(orow + c4 * 4) = o;
    }
    int t = threadIdx.x;
    if (t < RANK) {
        float tv = T[row * RANK + t];
        u16 hi = f2bf(tv);
        orow[DIM + t] = hi;
        orow[DIM + RANK + t] = f2bf(tv - bf2f(hi));
    } else if (t >= 32 && t < 64) {
        orow[DIM + t] = 0;
    }
}

// write T hi/lo + zero pad into existing bf16 [row][KE] buffer (o_ext)
__global__ __launch_bounds__(64) void pack_t_kernel(
    const float* __restrict__ T, u16* __restrict__ out)
{
    int row = blockIdx.x, t = threadIdx.x;
    u16* orow = out + (size_t)row * KE;
    if (t < RANK) {
        float tv = T[row * RANK + t];
        u16 hi = f2bf(tv);
        orow[DIM + t] = hi;
        orow[DIM + RANK + t] = f2bf(tv - bf2f(hi));
    } else if (t >= 32) {
        orow[DIM + t] = 0;
    }
}

// ---------------------------------------------------------------------------
// bf16 MFMA GEMM, 128x128 tile, BK=64 (32 KB LDS), LoRA folded into K.
// Block mapping is XCD-aware (bid&7 = XCD heuristic): each XCD owns a
// 4-mtile x (num_n/2) rectangle; m-inner order keeps its 3.2 MB A slab
// L2-resident while each W n-slab is consumed by 4 co-resident blocks once.
// MODE 0: C = A@W^T + bias -> fp32 [M][N]  (proj)
// MODE 1: qkv with fused RMSNorm+RoPE epilogue (q,k bf16 [2][NH][L][HD];
//   v bf16 [NH][HD][L] swizzled).
// ---------------------------------------------------------------------------
template<int MODE>
__global__ __launch_bounds__(256) void gemm_mfma_kernel(
    const u16* __restrict__ A, const u16* __restrict__ W,
    const float* __restrict__ bias,
    float* __restrict__ Cf,
    u16* __restrict__ qkbf, u16* __restrict__ vT,
    const float2* __restrict__ pe2,
    const float* __restrict__ q_scale, const float* __restrict__ k_scale,
    int M, int N, int K)
{
    __shared__ __align__(16) u16 a_s[128 * 64];   // 16 KB
    __shared__ __align__(16) u16 b_s[128 * 64];   // 16 KB

    int tid = threadIdx.x;
    int wave = tid >> 6, lane = tid & 63;
    int quad = lane >> 4, l15 = lane & 15;
    int wm = wave >> 1, wn = wave & 1;

    // XCD-aware mapping: num_m must be 16, num_n even.
    int num_n = N >> 7;
    int xcd = blockIdx.x & 7;
    int loc = blockIdx.x >> 3;
    int bm = (((xcd & 3) << 2) + (loc & 3)) << 7;
    int bn = ((xcd >> 2) * (num_n >> 1) + (loc >> 2)) << 7;

    // staging: 4 issues per matrix; 32 rows x 128 B per issue; chunk XOR swizzle
    const u16* ga[4]; const u16* gb[4];
    u16 *lA[4], *lB[4];
    #pragma unroll
    for (int e = 0; e < 4; e++) {
        int r = e * 32 + (tid >> 3);
        int g = (tid & 7) ^ (r & 7);
        ga[e] = A + (size_t)(bm + r) * K + g * 8;
        gb[e] = W + (size_t)(bn + r) * K + g * 8;
        lA[e] = &a_s[(e * 32 + wave * 8) * 64];
        lB[e] = &b_s[(e * 32 + wave * 8) * 64];
    }

    f32x4 acc[4][4];
    #pragma unroll
    for (int i = 0; i < 4; i++)
        #pragma unroll
        for (int j = 0; j < 4; j++) acc[i][j] = (f32x4){0.f, 0.f, 0.f, 0.f};

    int abase[4], bbase[4], co[2];
    #pragma unroll
    for (int i = 0; i < 4; i++) {
        abase[i] = (wm * 64 + i * 16 + l15) * 64;
        bbase[i] = (wn * 64 + i * 16 + l15) * 64;
    }
    #pragma unroll
    for (int ks = 0; ks < 2; ks++) co[ks] = ((ks * 4 + quad) ^ (l15 & 7)) * 8;

    for (int k0 = 0; k0 < K; k0 += 64) {
        #pragma unroll
        for (int e = 0; e < 4; e++) {
            GLOBAL_TO_LDS16(ga[e] + k0, lA[e]);
            GLOBAL_TO_LDS16(gb[e] + k0, lB[e]);
        }
        __syncthreads();
        #pragma unroll
        for (int ks = 0; ks < 2; ks++) {
            bf16x8 af[4], bf[4];
            #pragma unroll
            for (int i = 0; i < 4; i++) af[i] = *(const bf16x8*)&a_s[abase[i] + co[ks]];
            #pragma unroll
            for (int j = 0; j < 4; j++) bf[j] = *(const bf16x8*)&b_s[bbase[j] + co[ks]];
            #pragma unroll
            for (int i = 0; i < 4; i++)
                #pragma unroll
                for (int j = 0; j < 4; j++)
                    acc[i][j] = __builtin_amdgcn_mfma_f32_16x16x32_bf16(af[i], bf[j], acc[i][j], 0, 0, 0);
        }
        __syncthreads();
    }

    if (MODE == 0) {
        #pragma unroll
        for (int j = 0; j < 4; j++) {
            int col = bn + wn * 64 + j * 16 + l15;
            float bj = bias[col];
            #pragma unroll
            for (int i = 0; i < 4; i++)
                #pragma unroll
                for (int r = 0; r < 4; r++) {
                    int row = bm + wm * 64 + i * 16 + quad * 4 + r;
                    Cf[(size_t)row * N + col] = acc[i][j][r] + bj;
                }
        }
        return;
    }

    // ---- MODE 1: fused qkv epilogue ----
    int tn = bn >> 7;
    int mq = (tn >= 48) ? 2 : (tn >= 24 ? 1 : 0);
    int h = tn - mq * 24;

    #pragma unroll
    for (int j = 0; j < 4; j++) {
        float bj = bias[bn + wn * 64 + j * 16 + l15];
        #pragma unroll
        for (int i = 0; i < 4; i++)
            #pragma unroll
            for (int r = 0; r < 4; r++) acc[i][j][r] += bj;
    }

    if (mq == 2) {
        // V: store transposed [h][d][L] with chunk swizzle baked in
        #pragma unroll
        for (int j = 0; j < 4; j++) {
            int d = wn * 64 + j * 16 + l15;
            u16* vrow = vT + ((size_t)h * HD + d) * L_SEQ;
            #pragma unroll
            for (int i = 0; i < 4; i++)
                #pragma unroll
                for (int r = 0; r < 4; r++) {
                    int kv = bm + wm * 64 + i * 16 + quad * 4 + r;
                    int slot = ((kv >> 3) & 7) ^ (d & 7);
                    int colp = (kv & ~63) + slot * 8 + (kv & 7);
                    vrow[colp] = f2bf(acc[i][j][r]);
                }
        }
    } else {
        // per-row sum of squares over this wave's 64 cols
        float ssp[4][4];
        #pragma unroll
        for (int i = 0; i < 4; i++)
            #pragma unroll
            for (int r = 0; r < 4; r++) {
                float s = 0.f;
                #pragma unroll
                for (int j = 0; j < 4; j++) s = fmaf(acc[i][j][r], acc[i][j][r], s);
                #pragma unroll
                for (int mm = 8; mm; mm >>= 1) s += __shfl_xor(s, mm);
                ssp[i][r] = s;
            }
        float* ss_s = (float*)a_s;
        if (l15 == 0) {
            #pragma unroll
            for (int i = 0; i < 4; i++)
                *(float4*)&ss_s[wn * 128 + wm * 64 + i * 16 + quad * 4] =
                    make_float4(ssp[i][0], ssp[i][1], ssp[i][2], ssp[i][3]);
        }
        __syncthreads();
        float rfac[4][4];
        #pragma unroll
        for (int i = 0; i < 4; i++) {
            float4 s0 = *(const float4*)&ss_s[wm * 64 + i * 16 + quad * 4];
            float4 s1 = *(const float4*)&ss_s[128 + wm * 64 + i * 16 + quad * 4];
            rfac[i][0] = rsqrtf((s0.x + s1.x) * (1.f / HD) + 1e-6f);
            rfac[i][1] = rsqrtf((s0.y + s1.y) * (1.f / HD) + 1e-6f);
            rfac[i][2] = rsqrtf((s0.z + s1.z) * (1.f / HD) + 1e-6f);
            rfac[i][3] = rsqrtf((s0.w + s1.w) * (1.f / HD) + 1e-6f);
        }
        const float* scale = mq ? k_scale : q_scale;
        float sgn = (l15 & 1) ? 1.f : -1.f;
        u16* obase = qkbf + (size_t)(mq * NH + h) * L_SEQ * HD;
        #pragma unroll
        for (int j = 0; j < 4; j++) {
            int d = wn * 64 + j * 16 + l15;
            float sd = scale[d];
            #pragma unroll
            for (int i = 0; i < 4; i++)
                #pragma unroll
                for (int r = 0; r < 4; r++) {
                    int row = bm + wm * 64 + i * 16 + quad * 4 + r;
                    float t = acc[i][j][r] * rfac[i][r] * sd;
                    float tp = __shfl_xor(t, 1);
                    float2 cs = pe2[row * 64 + (d >> 1)];
                    float o = fmaf(cs.x, t, sgn * cs.y * tp);
                    obase[(size_t)row * HD + d] = f2bf(o);
                }
        }
    }
}

// ---------------------------------------------------------------------------
// bf16 MFMA flash attention, FIXED-max softmax (M = 64 log2-units; safe since
// RMSNorm bounds |q|=|k|=sqrt(128) -> |s|*sc <= 16.4 log2; fp is scale-free so
// the offset costs no precision). No online rescale, no per-iter shfls.
// XCD-grouped dispatch: bid&7 = XCD owns 3 heads (KV L2-resident).
// ---------------------------------------------------------------------------
__global__ __launch_bounds__(256) void attn_mfma_kernel(
    const u16* __restrict__ qk_bf, const u16* __restrict__ vT, u16* __restrict__ Og)
{
    __shared__ __align__(16) u16 k_s[64 * 128];    // 16 KB, [kv][d] 16-chunk swizzled
    __shared__ __align__(16) u16 v_s[128 * 64];    // 16 KB, [d][kv] 8-chunk swizzled
    __shared__ __align__(16) u16 p_s[4][16 * 72];  // 9 KB per-wave P

    int bid = blockIdx.x;
    int loc = bid >> 3;
    int h = (bid & 7) * 3 + (loc >> 5);
    int q0 = (loc & 31) * 64;
    int tid = threadIdx.x;
    int wave = tid >> 6, lane = tid & 63;
    int quad = lane >> 4, l15 = lane & 15;
    const u16* qb = qk_bf + (size_t)h * L_SEQ * HD;
    const u16* kb = qk_bf + (size_t)(NH + h) * L_SEQ * HD;
    const u16* vTh = vT + (size_t)h * HD * L_SEQ;

    bf16x8 aq[4];
    {
        const u16* qr = qb + (size_t)(q0 + wave * 16 + l15) * HD + quad * 8;
        #pragma unroll
        for (int ks = 0; ks < 4; ks++) aq[ks] = *(const bf16x8*)(qr + ks * 32);
    }

    f32x4 o_acc[8];
    #pragma unroll
    for (int n = 0; n < 8; n++) o_acc[n] = (f32x4){0.f, 0.f, 0.f, 0.f};
    float lsum[4] = {0.f, 0.f, 0.f, 0.f};
    const float sc = 0.08838834764831845f * 1.4426950408889634f;  // /sqrt(128)*log2e
    const float MB = 64.0f;                                       // fixed max, log2 units

    const u16* gk[4];
    #pragma unroll
    for (int e = 0; e < 4; e++) {
        int r = wave * 16 + e * 4 + (lane >> 4);
        int g = l15 ^ (r & 15);
        gk[e] = kb + (size_t)r * HD + g * 8;
    }
    const u16* gv[4];
    #pragma unroll
    for (int e = 0; e < 4; e++) {
        int d = wave * 32 + e * 8 + (lane >> 3);
        gv[e] = vTh + (size_t)d * L_SEQ + (lane & 7) * 8;
    }
    int vco[2];
    #pragma unroll
    for (int ks = 0; ks < 2; ks++) vco[ks] = ((ks * 4 + quad) ^ (l15 & 7)) * 8;

    for (int kv0 = 0; kv0 < L_SEQ; kv0 += 64) {
        __syncthreads();
        #pragma unroll
        for (int e = 0; e < 4; e++) {
            GLOBAL_TO_LDS16(gk[e] + (size_t)kv0 * HD, &k_s[(wave * 16 + e * 4) * 128]);
            GLOBAL_TO_LDS16(gv[e] + kv0, &v_s[(wave * 32 + e * 8) * 64]);
        }
        __syncthreads();

        // S = Q K^T
        f32x4 sacc[4];
        #pragma unroll
        for (int j = 0; j < 4; j++) sacc[j] = (f32x4){0.f, 0.f, 0.f, 0.f};
        #pragma unroll
        for (int ks = 0; ks < 4; ks++) {
            #pragma unroll
            for (int j = 0; j < 4; j++) {
                int n = j * 16 + l15;
                int slot = (ks * 4 + quad) ^ (n & 15);
                bf16x8 bk = *(const bf16x8*)&k_s[n * 128 + slot * 8];
                sacc[j] = __builtin_amdgcn_mfma_f32_16x16x32_bf16(aq[ks], bk, sacc[j], 0, 0, 0);
            }
        }

        // p = exp2(s*sc - MB); accumulate row sums; write P to LDS
        #pragma unroll
        for (int j = 0; j < 4; j++)
            #pragma unroll
            for (int r = 0; r < 4; r++) {
                float p = exp2f(fmaf(sacc[j][r], sc, -MB));
                sacc[j][r] = p;
                lsum[r] += p;
                p_s[wave][(quad * 4 + r) * 72 + j * 16 + l15] = f2bf(p);
            }
        bf16x8 ap[2];
        #pragma unroll
        for (int ks = 0; ks < 2; ks++)
            ap[ks] = *(const bf16x8*)&p_s[wave][l15 * 72 + ks * 32 + quad * 8];

        // O += P V  (no rescale — fixed max)
        #pragma unroll
        for (int ks = 0; ks < 2; ks++) {
            #pragma unroll
            for (int n = 0; n < 8; n++) {
                bf16x8 bv = *(const bf16x8*)&v_s[(n * 16 + l15) * 64 + vco[ks]];
                o_acc[n] = __builtin_amdgcn_mfma_f32_16x16x32_bf16(ap[ks], bv, o_acc[n], 0, 0, 0);
            }
        }
    }

    // single end-of-loop row-sum reduction across the 16-lane groups
    #pragma unroll
    for (int r = 0; r < 4; r++) {
        #pragma unroll
        for (int mm = 8; mm; mm >>= 1) lsum[r] += __shfl_xor(lsum[r], mm);
    }

    #pragma unroll
    for (int r = 0; r < 4; r++) {
        float inv = 1.f / lsum[r];
        int row = q0 + wave * 16 + quad * 4 + r;
        u16* orow = Og + (size_t)row * KE + h * HD;
        #pragma unroll
        for (int n = 0; n < 8; n++)
            orow[n * 16 + l15] = f2bf(o_acc[n][r] * inv);
    }
}

// ---------------------------------------------------------------------------
extern "C" void kernel_launch(void* const* d_in, const int* in_sizes, int n_in,
                              void* d_out, int out_size, void* d_ws, size_t ws_size,
                              hipStream_t stream)
{
    const float* x         = (const float*)d_in[0];
    const float* pe        = (const float*)d_in[1];
    const float* qkv_w     = (const float*)d_in[2];
    const float* qkv_b     = (const float*)d_in[3];
    const float* proj_w    = (const float*)d_in[4];
    const float* proj_b    = (const float*)d_in[5];
    const float* qkv_down  = (const float*)d_in[6];
    const float* qkv_up    = (const float*)d_in[7];
    const float* proj_down = (const float*)d_in[8];
    const float* proj_up   = (const float*)d_in[9];
    const float* q_scale   = (const float*)d_in[10];
    const float* k_scale   = (const float*)d_in[11];
    float* out = (float*)d_out;

    char* w = (char*)d_ws;
    u16*   qk_bf  = (u16*)w;    w += (size_t)2 * NH * L_SEQ * HD * 2;  // 25.2 MB
    u16*   vT_bf  = (u16*)w;    w += (size_t)NH * HD * L_SEQ * 2;      // 12.6 MB
    u16*   x_ext  = (u16*)w;    w += (size_t)L_SEQ * KE * 2;           // 12.8 MB
    u16*   wq_ext = (u16*)w;    w += (size_t)N_QKV * KE * 2;           // 57.8 MB
    u16*   wp_ext = (u16*)w;    w += (size_t)DIM * KE * 2;             // 19.3 MB
    u16*   o_ext  = (u16*)w;    w += (size_t)L_SEQ * KE * 2;           // 12.8 MB
    float2* pe2   = (float2*)w; w += (size_t)L_SEQ * 64 * sizeof(float2);
    float* t1     = (float*)w;  w += (size_t)L_SEQ * RANK * 4;
    float* t2     = (float*)w;

    pack_pe_kernel<<<L_SEQ, 64, 0, stream>>>(pe, pe2);
    pack_w_kernel<<<N_QKV, 256, 0, stream>>>(qkv_w, qkv_up, wq_ext);
    pack_w_kernel<<<DIM, 256, 0, stream>>>(proj_w, proj_up, wp_ext);
    lora_down_kernel<<<L_SEQ, 256, 0, stream>>>(x, qkv_down, t1);
    pack_x_kernel<<<L_SEQ, 256, 0, stream>>>(x, t1, x_ext);

    gemm_mfma_kernel<1><<<(N_QKV / 128) * (L_SEQ / 128), 256, 0, stream>>>(
        x_ext, wq_ext, qkv_b, nullptr, qk_bf, vT_bf, pe2, q_scale, k_scale,
        L_SEQ, N_QKV, KE);
    attn_mfma_kernel<<<(L_SEQ / 64) * NH, 256, 0, stream>>>(qk_bf, vT_bf, o_ext);
    lora_down_bf_kernel<<<L_SEQ, 256, 0, stream>>>(o_ext, proj_down, t2, KE);
    pack_t_kernel<<<L_SEQ, 64, 0, stream>>>(t2, o_ext);
    gemm_mfma_kernel<0><<<(DIM / 128) * (L_SEQ / 128), 256, 0, stream>>>(
        o_ext, wp_ext, proj_b, out, nullptr, nullptr, nullptr, nullptr, nullptr,
        L_SEQ, DIM, KE);
}